// Round 11
// baseline (282.391 us; speedup 1.0000x reference)
//
#include <hip/hip_runtime.h>

typedef __bf16 bf16;
typedef float f32x4 __attribute__((ext_vector_type(4)));
typedef bf16 bf16x8 __attribute__((ext_vector_type(8)));
typedef bf16 bf16x4 __attribute__((ext_vector_type(4)));
typedef unsigned int uint;
typedef unsigned short ushort;

// Problem constants: B=2 S=4096 D=768 H=12 HD=64 BLK=32 NBR=128 MB=24 NUM_BLOCK=1024 DIAG_N=3

__device__ __forceinline__ void llds16(const bf16* g, bf16* l) {
    __builtin_amdgcn_global_load_lds((const __attribute__((address_space(1))) uint*)g,
                                     (__attribute__((address_space(3))) uint*)l, 16, 0, 0);
}

__device__ __forceinline__ uint sortable(float f) {
    uint u = __float_as_uint(f);
    return u ^ (uint)(((int)u >> 31) | 0x80000000);
}

// ---------------- fused prep: X->bf16 conversion + masked block sums + token counts ----
// R10: grid (256 rows, 3 colgroups) x 256 threads; LDS tree-reduce over token quarters.
__global__ __launch_bounds__(256)
void k_prep(const float* __restrict__ X, const float* __restrict__ mask,
            bf16* __restrict__ Xb, float* __restrict__ Xh, float* __restrict__ tc) {
    const int row = blockIdx.x;                 // b*128 + nbr
    const int b = row >> 7, nbr = row & 127;
    const int g = blockIdx.y;                   // colgroup 0..2
    const int t = threadIdx.x;
    const int c = t & 63;                       // col within group
    const int tq = t >> 6;                      // token quarter 0..3
    const int c4 = g * 64 + c;                  // float4 column 0..191
    const size_t base = (size_t)(b * 4096 + nbr * 32) * 768;
    const float4* xp = (const float4*)(X + base) + c4;
    bf16x4* xbp = (bf16x4*)(Xb + base) + c4;
    const float* mp = mask + b * 4096 + nbr * 32;
    __shared__ float4 red[4][64];
    __shared__ float tcr[4];
    float4 s = {0.f, 0.f, 0.f, 0.f};
    float tcs = 0.f;
#pragma unroll
    for (int j = 0; j < 8; ++j) {
        const int tok = tq * 8 + j;
        float4 v = xp[(size_t)tok * 192];
        float m = mp[tok];
        s.x += v.x * m; s.y += v.y * m; s.z += v.z * m; s.w += v.w * m;
        tcs += m;
        bf16x4 o = {(bf16)v.x, (bf16)v.y, (bf16)v.z, (bf16)v.w};
        xbp[(size_t)tok * 192] = o;
    }
    red[tq][c] = s;
    if (c == 0) tcr[tq] = tcs;
    __syncthreads();
    if (tq == 0) {
        float4 a = red[0][c], b2 = red[1][c], c2 = red[2][c], d2 = red[3][c];
        float4 o = {a.x + b2.x + c2.x + d2.x, a.y + b2.y + c2.y + d2.y,
                    a.z + b2.z + c2.z + d2.z, a.w + b2.w + c2.w + d2.w};
        ((float4*)(Xh + (size_t)row * 768))[c4] = o;
        if (c == 0 && g == 0) tc[row] = tcr[0] + tcr[1] + tcr[2] + tcr[3];
    }
}

__global__ void k_convW(const float* __restrict__ Wq, const float* __restrict__ Wk,
                        const float* __restrict__ Wv, bf16* __restrict__ Wb) {
    int i = blockIdx.x * 256 + threadIdx.x;          // over 2304*768/4
    if (i >= 442368) return;
    int n = (i << 2) / 768;
    int k = (i << 2) % 768;
    const float* W = n < 768 ? Wq : (n < 1536 ? Wk : Wv);
    int nn = n - (n < 768 ? 0 : (n < 1536 ? 768 : 1536));
    float4 f = *(const float4*)(W + (size_t)nn * 768 + k);
    bf16x4 o = {(bf16)f.x, (bf16)f.y, (bf16)f.z, (bf16)f.w};
    ((bf16x4*)Wb)[i] = o;
}

// ---------------- QKV projection GEMM (bf16 MFMA, 256x128 tile, BK=64, XOR swizzle) ----
// R15 (resubmit; R10 was an infra failure, not a kernel result).
// Closes the R3 loop. R3 (BM=256, scattered 2B epilogue) blew WRITE 37->69MB and
// regressed; R11 proved the store path was the cause at BM=128. Retry BM=256 with
// R3's proven-correct K-loop verbatim + R11's coalesced LDS-transposed epilogue,
// executed in two 128-row halves reusing the 48KB K-loop LDS. 512 thr / 8 waves
// (4x2), per-wave 64x64 tile (identical fragments/swizzle), 2 blocks/CU,
// grid 32x18 = 576 blocks = 1.125 rounds. KEY counter: WRITE must stay ~37MB.
__global__ __launch_bounds__(512, 4)
void k_gemm_qkv(const bf16* __restrict__ Xb, const bf16* __restrict__ Wb,
                const float* __restrict__ bq, const float* __restrict__ bk,
                const float* __restrict__ bv, const float* __restrict__ mask,
                bf16* __restrict__ Qb, bf16* __restrict__ Kb, bf16* __restrict__ Vt) {
    __shared__ bf16 smem[24576];                 // K-loop: As[0..16384) Bs[16384..24576)
    bf16* As = smem;                             // epilogue: C half-tile [128][136]
    bf16* Bs = smem + 16384;
    const int tid = threadIdx.x;
    const int wave = tid >> 6, lane = tid & 63;
    const int quad = lane >> 4, l16 = lane & 15;
    const int wr = wave >> 1, wc = wave & 1;     // 4x2 wave grid, wave tile 64x64
    const int m0 = blockIdx.x * 256, n0 = blockIdx.y * 128;
    const int srow = lane >> 3;                              // row within 8-row chunk
    const int sgcol = (((lane & 7) ^ (srow & 7)) << 3);      // swizzled source col

    f32x4 acc[4][4] = {};

    for (int k0 = 0; k0 < 768; k0 += 64) {
        __syncthreads();
#pragma unroll
        for (int it = 0; it < 4; ++it) {             // A: 256 rows, 8 rows/call
            int R = wave * 32 + it * 8;
            llds16(Xb + (size_t)(m0 + R + srow) * 768 + k0 + sgcol, &As[R * 64]);
        }
#pragma unroll
        for (int it = 0; it < 2; ++it) {             // B: 128 rows
            int R = wave * 16 + it * 8;
            llds16(Wb + (size_t)(n0 + R + srow) * 768 + k0 + sgcol, &Bs[R * 64]);
        }
        __syncthreads();
#pragma unroll
        for (int ks = 0; ks < 2; ++ks) {
            const int pg = ((ks * 4 + quad) ^ (l16 & 7)) << 3;  // physical group offset
            bf16x8 a[4], b[4];
#pragma unroll
            for (int i = 0; i < 4; ++i)
                a[i] = *(const bf16x8*)&As[(wr * 64 + i * 16 + l16) * 64 + pg];
#pragma unroll
            for (int i = 0; i < 4; ++i)
                b[i] = *(const bf16x8*)&Bs[(wc * 64 + i * 16 + l16) * 64 + pg];
#pragma unroll
            for (int i = 0; i < 4; ++i)
#pragma unroll
                for (int j = 0; j < 4; ++j)
                    acc[i][j] = __builtin_amdgcn_mfma_f32_16x16x32_bf16(a[i], b[j], acc[i][j], 0, 0, 0);
        }
    }

    const int which = n0 / 768;                       // uniform per block
    const float* bias = which == 0 ? bq : (which == 1 ? bk : bv);

    __syncthreads();                                  // K-loop LDS reads done
    // two half-epilogues: waves wr in {2hf, 2hf+1} own rows [hf*128, hf*128+128)
#pragma unroll
    for (int hf = 0; hf < 2; ++hf) {
        if ((wr >> 1) == hf) {
            // deposit quadrant into LDS (Q/K: [s][col] ; V: [col(d)][s]), stride 136
#pragma unroll
            for (int i = 0; i < 4; ++i) {
                const int rloc0 = (wr & 1) * 64 + i * 16 + quad * 4;
#pragma unroll
                for (int j = 0; j < 4; ++j) {
                    const int cloc = wc * 64 + j * 16 + l16;
                    const int hcol = n0 - which * 768 + cloc;
                    const float bv_ = bias[hcol];
#pragma unroll
                    for (int r = 0; r < 4; ++r) {
                        const int rloc = rloc0 + r;
                        const int mm = m0 + hf * 128 + rloc;
                        const int bidx = mm >> 12, s = mm & 4095;
                        const float y = (acc[i][j][r] + bv_) * mask[(bidx << 12) + s];
                        if (which == 2) smem[cloc * 136 + rloc] = (bf16)y;
                        else            smem[rloc * 136 + cloc] = (bf16)y;
                    }
                }
            }
        }
        __syncthreads();
        // coalesced read-out: 2048 x 16B chunks, 4 per thread
        if (which < 2) {
            bf16* dst = which == 0 ? Qb : Kb;
#pragma unroll
            for (int it = 0; it < 4; ++it) {
                const int gidx = it * 512 + tid;
                const int sr = gidx >> 4, chunk = gidx & 15;
                const int mm = m0 + hf * 128 + sr;
                const int bidx = mm >> 12, s = mm & 4095;
                const int hcol = n0 - which * 768 + chunk * 8;
                const int hh = hcol >> 6, d0 = hcol & 63;
                bf16x8 v = *(const bf16x8*)&smem[sr * 136 + chunk * 8];
                *(bf16x8*)(dst + ((((size_t)(bidx * 12 + hh)) << 12) + s) * 64 + d0) = v;
            }
        } else {
#pragma unroll
            for (int it = 0; it < 4; ++it) {
                const int gidx = it * 512 + tid;
                const int drow = gidx >> 4, chunk = gidx & 15;
                const int s0 = chunk * 8;
                const int mm = m0 + hf * 128 + s0;
                const int bidx = mm >> 12, s = mm & 4095;   // s..s+7 within one 32-block
                const int hcol = n0 - 1536 + drow;
                const int hh = hcol >> 6, dd = hcol & 63;
                bf16x8 v = *(const bf16x8*)&smem[drow * 136 + s0];
                *(bf16x8*)(Vt + ((((size_t)(bidx * 12 + hh)) * 128 + (s >> 5)) * 64 + dd) * 32 + (s & 31)) = v;
            }
        }
        if (hf == 0) __syncthreads();                 // before half-1 overwrites the tile
    }
}

// ---------------- exact f32 low-res projections, register-tiled with k-split ----------
__global__ __launch_bounds__(256)
void k_lowres_p(const float* __restrict__ Xh,
                const float* __restrict__ Wq, const float* __restrict__ Wk,
                const float* __restrict__ Wv, float* __restrict__ partial) {
    const int nb = blockIdx.x;                  // 0..17 : 128-col tile of [q|k|v] weights
    const int rowbase = blockIdx.y * 128;       // 0 or 128
    const int bz = blockIdx.z;                  // k-chunk 0..6
    const int kb = bz * 112;
    const int klen = (bz == 6) ? 96 : 112;
    const int t = threadIdx.x;

    __shared__ float As[16 * 132];              // [k][row], +4 pad
    __shared__ float Bs[16 * 132];              // [k][col], +4 pad

    const int which = nb / 6;
    const float* Wsel = which == 0 ? Wq : (which == 1 ? Wk : Wv);
    const float* Wbase = Wsel + (size_t)((nb % 6) * 128) * 768;

    const int sr = t >> 2;                      // staging row/col (+64*i)
    const int skq = t & 3;                      // staging k-quad
    const int tr = t >> 4, tc2 = t & 15;
    const int r0 = tr * 8, c0 = tc2 * 8;

    float acc[8][8] = {};
    float4 va[2], vb[2];
    const int stages = klen >> 4;

#pragma unroll
    for (int i = 0; i < 2; ++i) {               // prologue: stage-0 loads
        va[i] = *(const float4*)(Xh + (size_t)(rowbase + sr + 64 * i) * 768 + kb + skq * 4);
        vb[i] = *(const float4*)(Wbase + (size_t)(sr + 64 * i) * 768 + kb + skq * 4);
    }

    for (int s = 0; s < stages; ++s) {
        __syncthreads();
#pragma unroll
        for (int i = 0; i < 2; ++i) {           // transposed LDS store (2-way bank, free)
            const int r = sr + 64 * i;
            As[(skq * 4 + 0) * 132 + r] = va[i].x;
            As[(skq * 4 + 1) * 132 + r] = va[i].y;
            As[(skq * 4 + 2) * 132 + r] = va[i].z;
            As[(skq * 4 + 3) * 132 + r] = va[i].w;
            Bs[(skq * 4 + 0) * 132 + r] = vb[i].x;
            Bs[(skq * 4 + 1) * 132 + r] = vb[i].y;
            Bs[(skq * 4 + 2) * 132 + r] = vb[i].z;
            Bs[(skq * 4 + 3) * 132 + r] = vb[i].w;
        }
        if (s + 1 < stages) {                   // prefetch next stage (hides under compute)
            const int kc = kb + (s + 1) * 16;
#pragma unroll
            for (int i = 0; i < 2; ++i) {
                va[i] = *(const float4*)(Xh + (size_t)(rowbase + sr + 64 * i) * 768 + kc + skq * 4);
                vb[i] = *(const float4*)(Wbase + (size_t)(sr + 64 * i) * 768 + kc + skq * 4);
            }
        }
        __syncthreads();
#pragma unroll
        for (int k = 0; k < 16; ++k) {
            float4 a0 = *(const float4*)&As[k * 132 + r0];
            float4 a1 = *(const float4*)&As[k * 132 + r0 + 4];
            float4 b0 = *(const float4*)&Bs[k * 132 + c0];
            float4 b1 = *(const float4*)&Bs[k * 132 + c0 + 4];
            float av[8] = {a0.x, a0.y, a0.z, a0.w, a1.x, a1.y, a1.z, a1.w};
            float bv[8] = {b0.x, b0.y, b0.z, b0.w, b1.x, b1.y, b1.z, b1.w};
#pragma unroll
            for (int i = 0; i < 8; ++i)
#pragma unroll
                for (int j = 0; j < 8; ++j)
                    acc[i][j] += av[i] * bv[j];
        }
    }

    float* pp = partial + (size_t)bz * 589824 + (size_t)(rowbase + r0) * 2304 + nb * 128 + c0;
#pragma unroll
    for (int i = 0; i < 8; ++i) {
        float4 s0 = {acc[i][0], acc[i][1], acc[i][2], acc[i][3]};
        float4 s1 = {acc[i][4], acc[i][5], acc[i][6], acc[i][7]};
        *(float4*)(pp + (size_t)i * 2304) = s0;
        *(float4*)(pp + (size_t)i * 2304 + 4) = s1;
    }
}

// ---------------- reduce k-split partials + bias + token-count div + scatter ----------
__global__ __launch_bounds__(256)
void k_lowfin(const float* __restrict__ partial, const float* __restrict__ tc,
              const float* __restrict__ bq, const float* __restrict__ bk,
              const float* __restrict__ bv,
              float* __restrict__ Qh, float* __restrict__ Kh, float* __restrict__ Vh) {
    const int gx = blockIdx.x;                  // 0..8 : 256-col group
    const int row = blockIdx.y;                 // 0..255
    const int t = threadIdx.x;
    const int gcol = gx * 256 + t;
    float s = 0.f;
#pragma unroll
    for (int ch = 0; ch < 7; ++ch)
        s += partial[(size_t)ch * 589824 + (size_t)row * 2304 + gcol];
    const int which = gx / 3;
    const int wcol = (gx % 3) * 256 + t;
    const float* bias = which == 0 ? bq : (which == 1 ? bk : bv);
    const float tcv = tc[row];
    const float val = (s + tcv * bias[wcol]) / (tcv + 1e-6f);
    const int b = row >> 7, nbr = row & 127;
    const int h = wcol >> 6, d = wcol & 63;
    float* dst = which == 0 ? Qh : (which == 1 ? Kh : Vh);
    dst[(((size_t)(b * 12 + h)) * 128 + nbr) * 64 + d] = val;
}

// ---------------- low-res logits + row max (f32 exact) ----------------
__global__ __launch_bounds__(256)
void k_lowlogit(const float* __restrict__ Qh, const float* __restrict__ Kh,
                float* __restrict__ prior, float* __restrict__ rowmax) {
    int mb = blockIdx.x, rc = blockIdx.y;             // grid (24, 8)
    int tid = threadIdx.x;
    __shared__ float Ksh[64 * 132];                   // [k][c] padded
    __shared__ float Qsh[16 * 64];
    for (int idx = tid; idx < 128 * 64; idx += 256) {
        int c = idx >> 6, k = idx & 63;
        Ksh[k * 132 + c] = Kh[((size_t)mb * 128 + c) * 64 + k];
    }
    for (int idx = tid; idx < 16 * 64; idx += 256) {
        int r = idx >> 6, k = idx & 63;
        Qsh[idx] = Qh[((size_t)mb * 128 + rc * 16 + r) * 64 + k];
    }
    __syncthreads();
    int rloc = tid >> 4, cg = tid & 15;
    float acc[8] = {};
    for (int k = 0; k < 64; ++k) {
        float qv = Qsh[rloc * 64 + k];
        const float* kr = &Ksh[k * 132 + cg * 8];
#pragma unroll
        for (int j = 0; j < 8; ++j) acc[j] += qv * kr[j];
    }
    float pm = -3.4e38f;
#pragma unroll
    for (int j = 0; j < 8; ++j) { acc[j] *= 0.125f; pm = fmaxf(pm, acc[j]); }
#pragma unroll
    for (int d = 1; d < 16; d <<= 1) pm = fmaxf(pm, __shfl_xor(pm, d, 64));
    int r = rc * 16 + rloc;
    if (cg == 0) rowmax[mb * 128 + r] = pm;
    float* dst = prior + ((size_t)mb * 128 + r) * 128 + cg * 8;
#pragma unroll
    for (int j = 0; j < 8; ++j) dst[j] = acc[j] - pm;
}

// ---------------- exact top-1024 threshold + list build (2-bit radix descent) --------
__global__ __launch_bounds__(1024)
void k_select(const float* __restrict__ prior, unsigned char* __restrict__ selmask,
              unsigned short* __restrict__ lists, int* __restrict__ counts,
              ushort* __restrict__ qorder) {
    const int mb = blockIdx.x, tid = threadIdx.x;
    const int ln = tid & 63;
    __shared__ int lc[16 * 3];                 // [level][field 3,2,1] counts
    __shared__ int cnt[128];
    if (tid < 48) lc[tid] = 0;
    if (tid < 128) cnt[tid] = 0;

    const int r = tid >> 3;                    // row (q-block) index, 8 threads/row
    const int cbase = (tid & 7) << 4;          // starting column
    uint key[16];
    const float4* P4 = (const float4*)(prior + (size_t)mb * 16384) + (tid << 2);
#pragma unroll
    for (int j4 = 0; j4 < 4; ++j4) {
        float4 v = P4[j4];
        float vv[4] = {v.x, v.y, v.z, v.w};
#pragma unroll
        for (int e = 0; e < 4; ++e) {
            int c = cbase + (j4 << 2) + e;
            float f = vv[e] + ((r - c <= 1 && c - r <= 1) ? 5e3f : 0.f);
            key[(j4 << 2) + e] = sortable(f);
        }
    }
    __syncthreads();                           // lc/cnt zeroed before use

    uint pfx = 0u;
    int k = 1024;
#pragma unroll
    for (int lvl = 0; lvl < 16; ++lvl) {
        const int sh = 30 - 2 * lvl;
        const uint maskA = (lvl == 0) ? 0u : (0xFFFFFFFFu << (sh + 2));
        int c3 = 0, c2 = 0, c1 = 0;
#pragma unroll
        for (int j = 0; j < 16; ++j) {
            uint x = key[j];
            bool m = ((x ^ pfx) & maskA) == 0u;
            uint f = (x >> sh) & 3u;
            c3 += (m && f == 3u);
            c2 += (m && f == 2u);
            c1 += (m && f == 1u);
        }
#pragma unroll
        for (int d = 1; d < 64; d <<= 1) {
            c3 += __shfl_xor(c3, d, 64);
            c2 += __shfl_xor(c2, d, 64);
            c1 += __shfl_xor(c1, d, 64);
        }
        if (ln == 0) {
            atomicAdd(&lc[lvl * 3 + 0], c3);
            atomicAdd(&lc[lvl * 3 + 1], c2);
            atomicAdd(&lc[lvl * 3 + 2], c1);
        }
        __syncthreads();
        const int C3 = lc[lvl * 3 + 0], C2 = lc[lvl * 3 + 1], C1 = lc[lvl * 3 + 2];
        uint choose;
        if (C3 >= k)                { choose = 3u; }
        else if (C3 + C2 >= k)      { choose = 2u; k -= C3; }
        else if (C3 + C2 + C1 >= k) { choose = 1u; k -= C3 + C2; }
        else                        { choose = 0u; k -= C3 + C2 + C1; }
        pfx |= choose << sh;
    }
    const uint T = pfx;                        // exact bit pattern of 1024th-largest prior

    uint packed[4] = {0u, 0u, 0u, 0u};
#pragma unroll
    for (int j = 0; j < 16; ++j) {
        if (key[j] >= T) {
            packed[j >> 2] |= 1u << ((j & 3) << 3);
            int pos = atomicAdd(&cnt[r], 1);
            lists[((size_t)mb * 128 + r) * 128 + pos] = (unsigned short)(cbase + j);
        }
    }
    uint4 pk;
    pk.x = packed[0]; pk.y = packed[1]; pk.z = packed[2]; pk.w = packed[3];
    *(uint4*)(selmask + (size_t)mb * 16384 + (size_t)tid * 16) = pk;
    __syncthreads();
    if (tid < 128) {
        const int myc = cnt[tid];
        counts[mb * 128 + tid] = myc;
        int rank = 0;
        for (int j = 0; j < 128; ++j) {        // broadcast LDS reads, O(128) per thread
            int cj = cnt[j];
            rank += (cj > myc) || (cj == myc && j < tid);
        }
        qorder[mb * 128 + rank] = (ushort)tid;
    }
}

// ---------------- low-res attention over non-selected blocks ----------------
__global__ __launch_bounds__(64)
void k_lowout(const float* __restrict__ prior, const unsigned char* __restrict__ selmask,
              const float* __restrict__ tc, const float* __restrict__ Vh,
              float* __restrict__ low_out, float* __restrict__ low_norm) {
    const int q = blockIdx.x & 127, mb = blockIdx.x >> 7;
    const int d = threadIdx.x;
    const float* pn = prior + ((size_t)mb * 128 + q) * 128;
    const uint4* smv = (const uint4*)(selmask + ((size_t)mb * 128 + q) * 128);
    uint sm32[32];
#pragma unroll
    for (int w = 0; w < 8; ++w) {
        uint4 u = smv[w];
        sm32[w * 4 + 0] = u.x; sm32[w * 4 + 1] = u.y;
        sm32[w * 4 + 2] = u.z; sm32[w * 4 + 3] = u.w;
    }
    const float* tcb = tc + (mb / 12) * 128;
    const float* Vb = Vh + (size_t)mb * 128 * 64;
    float acc = 0.f, nrm = 0.f;
#pragma unroll 4
    for (int c = 0; c < 128; ++c) {
        if (!((sm32[c >> 2] >> ((c & 3) << 3)) & 1u)) {
            float w = __expf(pn[c]) * tcb[c];
            acc += w * Vb[c * 64 + d];
            nrm += w;
        }
    }
    low_out[((size_t)mb * 128 + q) * 64 + d] = acc;
    if (d == 0) low_norm[mb * 128 + q] = nrm;
}

// ---------------- high-res sparse attention + fused combine epilogue ----------------
// R14 structure kept: XCD-locality swizzle + setprio + R13 unroll-2 pipeline.
__global__ __launch_bounds__(64)
void k_high(const bf16* __restrict__ Qb, const bf16* __restrict__ Kb,
            const bf16* __restrict__ Vt, const int* __restrict__ counts,
            const unsigned short* __restrict__ lists, const ushort* __restrict__ qorder,
            const float* __restrict__ rowmax, const float* __restrict__ low_out,
            const float* __restrict__ low_norm, const float* __restrict__ mask,
            float* __restrict__ out) {
    const int bid = blockIdx.x;
    const int work = ((bid & 7) * 384) + (bid >> 3);   // XCD-local mb grouping
    const int mb = work >> 7;
    const int q = qorder[mb * 128 + (work & 127)];
    const int lane = threadIdx.x, quad = lane >> 4, l16 = lane & 15;
    __shared__ bf16 Pa[32 * 40];
    __shared__ bf16 Pbs[32 * 40];

    const bf16* Qbase = Qb + ((size_t)mb * 4096 + q * 32) * 64;
    bf16x8 qf[2][2];
#pragma unroll
    for (int mt = 0; mt < 2; ++mt)
#pragma unroll
        for (int ks = 0; ks < 2; ++ks)
            qf[mt][ks] = *(const bf16x8*)(Qbase + (mt * 16 + l16) * 64 + ks * 32 + quad * 8);

    bf16x8 ones;
#pragma unroll
    for (int j = 0; j < 8; ++j) ones[j] = (bf16)1.0f;

    float mxl[2][4];                                   // per-lane raw logit max
    f32x4 o[2][4] = {};
    f32x4 lac[2] = {};                                 // row-sum accumulator (ones-MFMA)
#pragma unroll
    for (int mt = 0; mt < 2; ++mt)
#pragma unroll
        for (int r = 0; r < 4; ++r) mxl[mt][r] = -3.4e38f;

    int cntv = counts[mb * 128 + q];
    if (cntv > 128) cntv = 128;
    if (cntv < 1) cntv = 1;                            // diag band guarantees >=1
    const uint* lst32 = (const uint*)(lists + ((size_t)mb * 128 + q) * 128);

    const bf16* KB = Kb + (size_t)mb * 4096 * 64;
    const bf16* VB = Vt + (size_t)mb * 128 * 2048;

    int koff[2][2], voff[4];                           // per-lane elem offsets, reused
#pragma unroll
    for (int nt = 0; nt < 2; ++nt)
#pragma unroll
        for (int ks = 0; ks < 2; ++ks) koff[nt][ks] = (nt * 16 + l16) * 64 + ks * 32 + quad * 8;
#pragma unroll
    for (int nd = 0; nd < 4; ++nd) voff[nd] = (nd * 16 + l16) * 32 + quad * 8;

    bf16x8 kA[2][2], vA[4], kB[2][2], vB[4];
    {
        const uint pr = lst32[0];
        const int cA = __builtin_amdgcn_readfirstlane((int)(pr & 0xffffu));
        const bf16* kp = KB + (size_t)cA * 2048;
        const bf16* vp = VB + (size_t)cA * 2048;
#pragma unroll
        for (int nt = 0; nt < 2; ++nt)
#pragma unroll
            for (int ks = 0; ks < 2; ++ks) kA[nt][ks] = *(const bf16x8*)(kp + koff[nt][ks]);
#pragma unroll
        for (int nd = 0; nd < 4; ++nd) vA[nd] = *(const bf16x8*)(vp + voff[nd]);
        if (cntv > 1) {
            const int cB = __builtin_amdgcn_readfirstlane((int)(pr >> 16));
            const bf16* kp2 = KB + (size_t)cB * 2048;
            const bf16* vp2 = VB + (size_t)cB * 2048;
#pragma unroll
            for (int nt = 0; nt < 2; ++nt)
#pragma unroll
                for (int ks = 0; ks < 2; ++ks) kB[nt][ks] = *(const bf16x8*)(kp2 + koff[nt][ks]);
#pragma unroll
            for (int nd = 0; nd < 4; ++nd) vB[nd] = *(const bf16x8*)(vp2 + voff[nd]);
        }
    }

    for (int i = 0; i < cntv; i += 2) {
        const bool hasB = (i + 1 < cntv);
        const bool hasAn = (i + 2 < cntv);
        const bool hasBn = (i + 3 < cntv);
        int cAn = 0, cBn = 0;
        if (hasAn) {
            const uint prn = lst32[(i >> 1) + 1];
            cAn = __builtin_amdgcn_readfirstlane((int)(prn & 0xffffu));
            cBn = __builtin_amdgcn_readfirstlane((int)(prn >> 16));
        }

        // ---- QK + exp/store, item A ----
        {
            f32x4 sf[2][2] = {};
            __builtin_amdgcn_s_setprio(1);
#pragma unroll
            for (int mt = 0; mt < 2; ++mt)
#pragma unroll
                for (int nt = 0; nt < 2; ++nt) {
                    sf[mt][nt] = __builtin_amdgcn_mfma_f32_16x16x32_bf16(qf[mt][0], kA[nt][0], sf[mt][nt], 0, 0, 0);
                    sf[mt][nt] = __builtin_amdgcn_mfma_f32_16x16x32_bf16(qf[mt][1], kA[nt][1], sf[mt][nt], 0, 0, 0);
                }
            __builtin_amdgcn_s_setprio(0);
#pragma unroll
            for (int mt = 0; mt < 2; ++mt)
#pragma unroll
                for (int r = 0; r < 4; ++r) {
                    mxl[mt][r] = fmaxf(mxl[mt][r], fmaxf(sf[mt][0][r], sf[mt][1][r]));
                    float e0, e1;
                    asm("v_exp_f32 %0, %1" : "=v"(e0) : "v"(sf[mt][0][r] * 0.18033688011112042f));
                    asm("v_exp_f32 %0, %1" : "=v"(e1) : "v"(sf[mt][1][r] * 0.18033688011112042f));
                    Pa[(mt * 16 + quad * 4 + r) * 40 + l16] = (bf16)e0;
                    Pa[(mt * 16 + quad * 4 + r) * 40 + 16 + l16] = (bf16)e1;
                }
        }
        // ---- QK + exp/store, item B ----
        if (hasB) {
            f32x4 sf[2][2] = {};
            __builtin_amdgcn_s_setprio(1);
#pragma unroll
            for (int mt = 0; mt < 2; ++mt)
#pragma unroll
                for (int nt = 0; nt < 2; ++nt) {
                    sf[mt][nt] = __builtin_amdgcn_mfma_f32_16x16x32_bf16(qf[mt][0], kB[nt][0], sf[mt][nt], 0, 0, 0);
                    sf[mt][nt] = __builtin_amdgcn_mfma_f32_16x16x32_bf16(qf[mt][1], kB[nt][1], sf[mt][nt], 0, 0, 0);
                }
            __builtin_amdgcn_s_setprio(0);
#pragma unroll
            for (int mt = 0; mt < 2; ++mt)
#pragma unroll
                for (int r = 0; r < 4; ++r) {
                    mxl[mt][r] = fmaxf(mxl[mt][r], fmaxf(sf[mt][0][r], sf[mt][1][r]));
                    float e0, e1;
                    asm("v_exp_f32 %0, %1" : "=v"(e0) : "v"(sf[mt][0][r] * 0.18033688011112042f));
                    asm("v_exp_f32 %0, %1" : "=v"(e1) : "v"(sf[mt][1][r] * 0.18033688011112042f));
                    Pbs[(mt * 16 + quad * 4 + r) * 40 + l16] = (bf16)e0;
                    Pbs[(mt * 16 + quad * 4 + r) * 40 + 16 + l16] = (bf16)e1;
                }
        }

        // K prefetch for next pair (kA/kB now dead)
        if (hasAn) {
            const bf16* kp = KB + (size_t)cAn * 2048;
#pragma unroll
            for (int nt = 0; nt < 2; ++nt)
#pragma unroll
                for (int ks = 0; ks < 2; ++ks) kA[nt][ks] = *(const bf16x8*)(kp + koff[nt][ks]);
        }
        if (hasBn) {
            const bf16* kp = KB + (size_t)cBn * 2048;
#pragma unroll
            for (int nt = 0; nt < 2; ++nt)
#pragma unroll
                for (int ks = 0; ks < 2; ++ks) kB[nt][ks] = *(const bf16x8*)(kp + koff[nt][ks]);
        }

        // single drain for both P slices (same-wave DS ops are in-order)
        asm volatile("s_waitcnt lgkmcnt(0)" ::: "memory");
        bf16x8 pa[2], pb[2];
#pragma unroll
        for (int mt = 0; mt < 2; ++mt)
            pa[mt] = *(const bf16x8*)&Pa[(mt * 16 + l16) * 40 + quad * 8];
        if (hasB) {
#pragma unroll
            for (int mt = 0; mt < 2; ++mt)
                pb[mt] = *(const bf16x8*)&Pbs[(mt * 16 + l16) * 40 + quad * 8];
        }
        __builtin_amdgcn_s_setprio(1);
#pragma unroll
        for (int mt = 0; mt < 2; ++mt) {
#pragma unroll
            for (int nd = 0; nd < 4; ++nd)
                o[mt][nd] = __builtin_amdgcn_mfma_f32_16x16x32_bf16(pa[mt], vA[nd], o[mt][nd], 0, 0, 0);
            lac[mt] = __builtin_amdgcn_mfma_f32_16x16x32_bf16(pa[mt], ones, lac[mt], 0, 0, 0);
        }
        if (hasB) {
#pragma unroll
            for (int mt = 0; mt < 2; ++mt) {
#pragma unroll
                for (int nd = 0; nd < 4; ++nd)
                    o[mt][nd] = __builtin_amdgcn_mfma_f32_16x16x32_bf16(pb[mt], vB[nd], o[mt][nd], 0, 0, 0);
                lac[mt] = __builtin_amdgcn_mfma_f32_16x16x32_bf16(pb[mt], ones, lac[mt], 0, 0, 0);
            }
        }
        __builtin_amdgcn_s_setprio(0);

        // V prefetch for next pair (vA/vB now dead)
        if (hasAn) {
            const bf16* vp = VB + (size_t)cAn * 2048;
#pragma unroll
            for (int nd = 0; nd < 4; ++nd) vA[nd] = *(const bf16x8*)(vp + voff[nd]);
        }
        if (hasBn) {
            const bf16* vp = VB + (size_t)cBn * 2048;
#pragma unroll
            for (int nd = 0; nd < 4; ++nd) vB[nd] = *(const bf16x8*)(vp + voff[nd]);
        }
    }

    // one-time 16-lane max reduction (raw logits; *0.125 afterwards is exact)
#pragma unroll
    for (int d = 1; d < 16; d <<= 1)
#pragma unroll
        for (int mt = 0; mt < 2; ++mt)
#pragma unroll
            for (int r = 0; r < 4; ++r)
                mxl[mt][r] = fmaxf(mxl[mt][r], __shfl_xor(mxl[mt][r], d, 64));

    // ---- fused combine epilogue (shift folded into hcf) ----
    const int b = mb / 12, h = mb - b * 12;
    const float rm = rowmax[mb * 128 + q];
    const float ln = low_norm[mb * 128 + q];
    const float* LO = low_out + ((size_t)mb * 128 + q) * 64;
#pragma unroll
    for (int mt = 0; mt < 2; ++mt)
#pragma unroll
        for (int r = 0; r < 4; ++r) {
            const int s = q * 32 + mt * 16 + quad * 4 + r;
            const float mv = fmaxf(mxl[mt][r] * 0.125f, -1e6f);
            const float hn = lac[mt][r];
            const float mk = mask[(b << 12) + s];
            const float lcr = (rm - mv) * mk;
            const float lcf = __expf(fminf(lcr, 0.f));
            const float hcf = __expf(-mv - fmaxf(lcr, 0.f));   // exp(-mv)*ref_hcf
            const float den = 1.0f / (hn * hcf + ln * lcf + 1e-6f);
            float* op = out + ((size_t)(b * 4096 + s)) * 768 + h * 64;
#pragma unroll
            for (int nd = 0; nd < 4; ++nd) {
                const int d = nd * 16 + l16;
                op[d] = (o[mt][nd][r] * hcf + LO[d] * lcf) * den;
            }
        }
}

extern "C" void kernel_launch(void* const* d_in, const int* in_sizes, int n_in,
                              void* d_out, int out_size, void* d_ws, size_t ws_size,
                              hipStream_t stream) {
    (void)in_sizes; (void)n_in; (void)out_size; (void)ws_size;
    const float* X    = (const float*)d_in[0];
    const float* mask = (const float*)d_in[1];
    const float* Wq   = (const float*)d_in[2];
    const float* bq   = (const float*)d_in[3];
    const float* Wk   = (const float*)d_in[4];
    const float* bk   = (const float*)d_in[5];
    const float* Wv   = (const float*)d_in[6];
    const float* bv   = (const float*)d_in[7];
    float* out = (float*)d_out;

    char* ws = (char*)d_ws;
    size_t off = 0;
    auto alloc = [&](size_t bytes) -> void* {
        off = (off + 255) & ~(size_t)255;
        void* p = ws + off;
        off += bytes;
        return p;
    };
    bf16* Xb  = (bf16*)alloc((size_t)8192 * 768 * 2);
    bf16* Wb  = (bf16*)alloc((size_t)2304 * 768 * 2);
    bf16* Qb  = (bf16*)alloc((size_t)24 * 4096 * 64 * 2);
    bf16* Kb  = (bf16*)alloc((size_t)24 * 4096 * 64 * 2);
    bf16* Vt  = (bf16*)alloc((size_t)24 * 4096 * 64 * 2);
    float* Xh = (float*)alloc((size_t)256 * 768 * 4);
    float* tc = (float*)alloc(256 * 4);
    float* Qh = (float*)alloc((size_t)24 * 128 * 64 * 4);
    float* Kh = (float*)alloc((size_t)24 * 128 * 64 * 4);
    float* Vh = (float*)alloc((size_t)24 * 128 * 64 * 4);
    float* prior = (float*)alloc((size_t)24 * 16384 * 4);
    float* rowmax = (float*)alloc(24 * 128 * 4);
    unsigned char* selmask = (unsigned char*)alloc((size_t)24 * 16384);
    unsigned short* lists = (unsigned short*)alloc((size_t)24 * 128 * 128 * 2);
    int* counts = (int*)alloc(24 * 128 * 4);
    ushort* qorder = (ushort*)alloc(24 * 128 * 2);
    float* low_out   = (float*)alloc((size_t)24 * 128 * 64 * 4);
    float* low_norm  = (float*)alloc(24 * 128 * 4);
    float* partial   = (float*)alloc((size_t)7 * 589824 * 4);   // k-split partials, 16.5 MB

    k_prep<<<dim3(256, 3), 256, 0, stream>>>(X, mask, Xb, Xh, tc);
    k_convW<<<1728, 256, 0, stream>>>(Wq, Wk, Wv, Wb);
    k_gemm_qkv<<<dim3(32, 18), 512, 0, stream>>>(Xb, Wb, bq, bk, bv, mask, Qb, Kb, Vt);
    k_lowres_p<<<dim3(18, 2, 7), 256, 0, stream>>>(Xh, Wq, Wk, Wv, partial);
    k_lowfin<<<dim3(9, 256), 256, 0, stream>>>(partial, tc, bq, bk, bv, Qh, Kh, Vh);
    k_lowlogit<<<dim3(24, 8), 256, 0, stream>>>(Qh, Kh, prior, rowmax);
    k_select<<<24, 1024, 0, stream>>>(prior, selmask, lists, counts, qorder);
    k_lowout<<<3072, 64, 0, stream>>>(prior, selmask, tc, Vh, low_out, low_norm);
    k_high<<<3072, 64, 0, stream>>>(Qb, Kb, Vt, counts, lists, qorder, rowmax, low_out,
                                    low_norm, mask, out);
}

// Round 12
// 260.420 us; speedup vs baseline: 1.0844x; 1.0844x over previous
//
#include <hip/hip_runtime.h>

typedef __bf16 bf16;
typedef float f32x4 __attribute__((ext_vector_type(4)));
typedef bf16 bf16x8 __attribute__((ext_vector_type(8)));
typedef bf16 bf16x4 __attribute__((ext_vector_type(4)));
typedef unsigned int uint;
typedef unsigned short ushort;

// Problem constants: B=2 S=4096 D=768 H=12 HD=64 BLK=32 NBR=128 MB=24 NUM_BLOCK=1024 DIAG_N=3

__device__ __forceinline__ void llds16(const bf16* g, bf16* l) {
    __builtin_amdgcn_global_load_lds((const __attribute__((address_space(1))) uint*)g,
                                     (__attribute__((address_space(3))) uint*)l, 16, 0, 0);
}

__device__ __forceinline__ uint sortable(float f) {
    uint u = __float_as_uint(f);
    return u ^ (uint)(((int)u >> 31) | 0x80000000);
}

// ---------------- fused prep: X->bf16 + masked block sums + token counts + W->bf16 ----
// R16: k_convW merged in (blockIdx partition) — one fewer serial launch.
__global__ __launch_bounds__(256)
void k_prep(const float* __restrict__ X, const float* __restrict__ mask,
            const float* __restrict__ Wq, const float* __restrict__ Wk,
            const float* __restrict__ Wv,
            bf16* __restrict__ Xb, float* __restrict__ Xh, float* __restrict__ tc,
            bf16* __restrict__ Wb) {
    const int p = blockIdx.x;
    const int t = threadIdx.x;
    if (p >= 768) {                             // ---- W conversion part (1728 blocks) ----
        int i = (p - 768) * 256 + t;            // over 2304*768/4
        if (i >= 442368) return;
        int n = (i << 2) / 768;
        int k = (i << 2) % 768;
        const float* W = n < 768 ? Wq : (n < 1536 ? Wk : Wv);
        int nn = n - (n < 768 ? 0 : (n < 1536 ? 768 : 1536));
        float4 f = *(const float4*)(W + (size_t)nn * 768 + k);
        bf16x4 o = {(bf16)f.x, (bf16)f.y, (bf16)f.z, (bf16)f.w};
        ((bf16x4*)Wb)[i] = o;
        return;
    }
    const int row = p % 256;                    // b*128 + nbr
    const int g = p / 256;                      // colgroup 0..2
    const int b = row >> 7, nbr = row & 127;
    const int c = t & 63;                       // col within group
    const int tq = t >> 6;                      // token quarter 0..3
    const int c4 = g * 64 + c;                  // float4 column 0..191
    const size_t base = (size_t)(b * 4096 + nbr * 32) * 768;
    const float4* xp = (const float4*)(X + base) + c4;
    bf16x4* xbp = (bf16x4*)(Xb + base) + c4;
    const float* mp = mask + b * 4096 + nbr * 32;
    __shared__ float4 red[4][64];
    __shared__ float tcr[4];
    float4 s = {0.f, 0.f, 0.f, 0.f};
    float tcs = 0.f;
#pragma unroll
    for (int j = 0; j < 8; ++j) {
        const int tok = tq * 8 + j;
        float4 v = xp[(size_t)tok * 192];
        float m = mp[tok];
        s.x += v.x * m; s.y += v.y * m; s.z += v.z * m; s.w += v.w * m;
        tcs += m;
        bf16x4 o = {(bf16)v.x, (bf16)v.y, (bf16)v.z, (bf16)v.w};
        xbp[(size_t)tok * 192] = o;
    }
    red[tq][c] = s;
    if (c == 0) tcr[tq] = tcs;
    __syncthreads();
    if (tq == 0) {
        float4 a = red[0][c], b2 = red[1][c], c2 = red[2][c], d2 = red[3][c];
        float4 o = {a.x + b2.x + c2.x + d2.x, a.y + b2.y + c2.y + d2.y,
                    a.z + b2.z + c2.z + d2.z, a.w + b2.w + c2.w + d2.w};
        ((float4*)(Xh + (size_t)row * 768))[c4] = o;
        if (c == 0 && g == 0) tc[row] = tcr[0] + tcr[1] + tcr[2] + tcr[3];
    }
}

// ---------------- QKV projection GEMM (bf16 MFMA, 128x128 tile, BK=64, XOR swizzle) ----
// R16: exact revert to the R8-proven version (43.7us). BM=256 is condemned twice
// (R3: 87us scattered stores; R15: 64.5us even with coalesced stores, WRITE 37->50MB,
// FETCH 26->32MB — the 256-row tile's footprint itself degrades L2 residency).
// K-loop = R1; coalesced LDS-transposed epilogue = R11.
__global__ __launch_bounds__(256, 4)
void k_gemm_qkv(const bf16* __restrict__ Xb, const bf16* __restrict__ Wb,
                const float* __restrict__ bq, const float* __restrict__ bk,
                const float* __restrict__ bv, const float* __restrict__ mask,
                bf16* __restrict__ Qb, bf16* __restrict__ Kb, bf16* __restrict__ Vt) {
    __shared__ bf16 smem[17408];                 // K-loop: As[0..8192) Bs[8192..16384)
    bf16* As = smem;                             // epilogue: C tile [128][136]
    bf16* Bs = smem + 8192;
    const int tid = threadIdx.x;
    const int wave = tid >> 6, lane = tid & 63;
    const int quad = lane >> 4, l16 = lane & 15;
    const int wr = wave >> 1, wc = wave & 1;
    const int m0 = blockIdx.x * 128, n0 = blockIdx.y * 128;
    const int srow = lane >> 3;                              // row within 8-row chunk
    const int sgcol = (((lane & 7) ^ (srow & 7)) << 3);      // swizzled source col

    f32x4 acc[4][4] = {};

    for (int k0 = 0; k0 < 768; k0 += 64) {
        __syncthreads();
#pragma unroll
        for (int it = 0; it < 4; ++it) {
            int R = wave * 32 + it * 8;
            llds16(Xb + (size_t)(m0 + R + srow) * 768 + k0 + sgcol, &As[R * 64]);
            llds16(Wb + (size_t)(n0 + R + srow) * 768 + k0 + sgcol, &Bs[R * 64]);
        }
        __syncthreads();
#pragma unroll
        for (int ks = 0; ks < 2; ++ks) {
            const int pg = ((ks * 4 + quad) ^ (l16 & 7)) << 3;  // physical group offset
            bf16x8 a[4], b[4];
#pragma unroll
            for (int i = 0; i < 4; ++i)
                a[i] = *(const bf16x8*)&As[(wr * 64 + i * 16 + l16) * 64 + pg];
#pragma unroll
            for (int i = 0; i < 4; ++i)
                b[i] = *(const bf16x8*)&Bs[(wc * 64 + i * 16 + l16) * 64 + pg];
#pragma unroll
            for (int i = 0; i < 4; ++i)
#pragma unroll
                for (int j = 0; j < 4; ++j)
                    acc[i][j] = __builtin_amdgcn_mfma_f32_16x16x32_bf16(a[i], b[j], acc[i][j], 0, 0, 0);
        }
    }

    const int which = n0 / 768;                       // uniform per block
    const float* bias = which == 0 ? bq : (which == 1 ? bk : bv);

    __syncthreads();                                  // K-loop LDS reads done
    // deposit quadrant into LDS (Q/K: [s][col] ; V: [col(d)][s]), stride 136
#pragma unroll
    for (int i = 0; i < 4; ++i) {
        const int rloc0 = wr * 64 + i * 16 + quad * 4;
#pragma unroll
        for (int j = 0; j < 4; ++j) {
            const int cloc = wc * 64 + j * 16 + l16;
            const int hcol = n0 - which * 768 + cloc;
            const float bv_ = bias[hcol];
#pragma unroll
            for (int r = 0; r < 4; ++r) {
                const int rloc = rloc0 + r;
                const int mm = m0 + rloc;
                const int bidx = mm >> 12, s = mm & 4095;
                const float y = (acc[i][j][r] + bv_) * mask[(bidx << 12) + s];
                if (which == 2) smem[cloc * 136 + rloc] = (bf16)y;
                else            smem[rloc * 136 + cloc] = (bf16)y;
            }
        }
    }
    __syncthreads();
    // coalesced read-out: 2048 x 16B chunks, 8 per thread
    if (which < 2) {
        bf16* dst = which == 0 ? Qb : Kb;
#pragma unroll
        for (int it = 0; it < 8; ++it) {
            const int gidx = it * 256 + tid;
            const int sr = gidx >> 4, chunk = gidx & 15;
            const int mm = m0 + sr;
            const int bidx = mm >> 12, s = mm & 4095;
            const int hcol = n0 - which * 768 + chunk * 8;
            const int h = hcol >> 6, d0 = hcol & 63;
            bf16x8 v = *(const bf16x8*)&smem[sr * 136 + chunk * 8];
            *(bf16x8*)(dst + ((((size_t)(bidx * 12 + h)) << 12) + s) * 64 + d0) = v;
        }
    } else {
#pragma unroll
        for (int it = 0; it < 8; ++it) {
            const int gidx = it * 256 + tid;
            const int drow = gidx >> 4, chunk = gidx & 15;
            const int s0 = chunk * 8;
            const int mm = m0 + s0;
            const int bidx = mm >> 12, s = mm & 4095;     // s..s+7 within one 32-block
            const int hcol = n0 - 1536 + drow;
            const int h = hcol >> 6, dd = hcol & 63;
            bf16x8 v = *(const bf16x8*)&smem[drow * 136 + s0];
            *(bf16x8*)(Vt + ((((size_t)(bidx * 12 + h)) * 128 + (s >> 5)) * 64 + dd) * 32 + (s & 31)) = v;
        }
    }
}

// ---------------- exact f32 low-res projections, register-tiled with k-split ----------
__global__ __launch_bounds__(256)
void k_lowres_p(const float* __restrict__ Xh,
                const float* __restrict__ Wq, const float* __restrict__ Wk,
                const float* __restrict__ Wv, float* __restrict__ partial) {
    const int nb = blockIdx.x;                  // 0..17 : 128-col tile of [q|k|v] weights
    const int rowbase = blockIdx.y * 128;       // 0 or 128
    const int bz = blockIdx.z;                  // k-chunk 0..6
    const int kb = bz * 112;
    const int klen = (bz == 6) ? 96 : 112;
    const int t = threadIdx.x;

    __shared__ float As[16 * 132];              // [k][row], +4 pad
    __shared__ float Bs[16 * 132];              // [k][col], +4 pad

    const int which = nb / 6;
    const float* Wsel = which == 0 ? Wq : (which == 1 ? Wk : Wv);
    const float* Wbase = Wsel + (size_t)((nb % 6) * 128) * 768;

    const int sr = t >> 2;                      // staging row/col (+64*i)
    const int skq = t & 3;                      // staging k-quad
    const int tr = t >> 4, tc2 = t & 15;
    const int r0 = tr * 8, c0 = tc2 * 8;

    float acc[8][8] = {};
    float4 va[2], vb[2];
    const int stages = klen >> 4;

#pragma unroll
    for (int i = 0; i < 2; ++i) {               // prologue: stage-0 loads
        va[i] = *(const float4*)(Xh + (size_t)(rowbase + sr + 64 * i) * 768 + kb + skq * 4);
        vb[i] = *(const float4*)(Wbase + (size_t)(sr + 64 * i) * 768 + kb + skq * 4);
    }

    for (int s = 0; s < stages; ++s) {
        __syncthreads();
#pragma unroll
        for (int i = 0; i < 2; ++i) {           // transposed LDS store (2-way bank, free)
            const int r = sr + 64 * i;
            As[(skq * 4 + 0) * 132 + r] = va[i].x;
            As[(skq * 4 + 1) * 132 + r] = va[i].y;
            As[(skq * 4 + 2) * 132 + r] = va[i].z;
            As[(skq * 4 + 3) * 132 + r] = va[i].w;
            Bs[(skq * 4 + 0) * 132 + r] = vb[i].x;
            Bs[(skq * 4 + 1) * 132 + r] = vb[i].y;
            Bs[(skq * 4 + 2) * 132 + r] = vb[i].z;
            Bs[(skq * 4 + 3) * 132 + r] = vb[i].w;
        }
        if (s + 1 < stages) {                   // prefetch next stage (hides under compute)
            const int kc = kb + (s + 1) * 16;
#pragma unroll
            for (int i = 0; i < 2; ++i) {
                va[i] = *(const float4*)(Xh + (size_t)(rowbase + sr + 64 * i) * 768 + kc + skq * 4);
                vb[i] = *(const float4*)(Wbase + (size_t)(sr + 64 * i) * 768 + kc + skq * 4);
            }
        }
        __syncthreads();
#pragma unroll
        for (int k = 0; k < 16; ++k) {
            float4 a0 = *(const float4*)&As[k * 132 + r0];
            float4 a1 = *(const float4*)&As[k * 132 + r0 + 4];
            float4 b0 = *(const float4*)&Bs[k * 132 + c0];
            float4 b1 = *(const float4*)&Bs[k * 132 + c0 + 4];
            float av[8] = {a0.x, a0.y, a0.z, a0.w, a1.x, a1.y, a1.z, a1.w};
            float bv[8] = {b0.x, b0.y, b0.z, b0.w, b1.x, b1.y, b1.z, b1.w};
#pragma unroll
            for (int i = 0; i < 8; ++i)
#pragma unroll
                for (int j = 0; j < 8; ++j)
                    acc[i][j] += av[i] * bv[j];
        }
    }

    float* pp = partial + (size_t)bz * 589824 + (size_t)(rowbase + r0) * 2304 + nb * 128 + c0;
#pragma unroll
    for (int i = 0; i < 8; ++i) {
        float4 s0 = {acc[i][0], acc[i][1], acc[i][2], acc[i][3]};
        float4 s1 = {acc[i][4], acc[i][5], acc[i][6], acc[i][7]};
        *(float4*)(pp + (size_t)i * 2304) = s0;
        *(float4*)(pp + (size_t)i * 2304 + 4) = s1;
    }
}

// ---------------- reduce k-split partials + bias + token-count div + scatter ----------
__global__ __launch_bounds__(256)
void k_lowfin(const float* __restrict__ partial, const float* __restrict__ tc,
              const float* __restrict__ bq, const float* __restrict__ bk,
              const float* __restrict__ bv,
              float* __restrict__ Qh, float* __restrict__ Kh, float* __restrict__ Vh) {
    const int gx = blockIdx.x;                  // 0..8 : 256-col group
    const int row = blockIdx.y;                 // 0..255
    const int t = threadIdx.x;
    const int gcol = gx * 256 + t;
    float s = 0.f;
#pragma unroll
    for (int ch = 0; ch < 7; ++ch)
        s += partial[(size_t)ch * 589824 + (size_t)row * 2304 + gcol];
    const int which = gx / 3;
    const int wcol = (gx % 3) * 256 + t;
    const float* bias = which == 0 ? bq : (which == 1 ? bk : bv);
    const float tcv = tc[row];
    const float val = (s + tcv * bias[wcol]) / (tcv + 1e-6f);
    const int b = row >> 7, nbr = row & 127;
    const int h = wcol >> 6, d = wcol & 63;
    float* dst = which == 0 ? Qh : (which == 1 ? Kh : Vh);
    dst[(((size_t)(b * 12 + h)) * 128 + nbr) * 64 + d] = val;
}

// ---------------- low-res logits + row max (f32 exact) ----------------
__global__ __launch_bounds__(256)
void k_lowlogit(const float* __restrict__ Qh, const float* __restrict__ Kh,
                float* __restrict__ prior, float* __restrict__ rowmax) {
    int mb = blockIdx.x, rc = blockIdx.y;             // grid (24, 8)
    int tid = threadIdx.x;
    __shared__ float Ksh[64 * 132];                   // [k][c] padded
    __shared__ float Qsh[16 * 64];
    for (int idx = tid; idx < 128 * 64; idx += 256) {
        int c = idx >> 6, k = idx & 63;
        Ksh[k * 132 + c] = Kh[((size_t)mb * 128 + c) * 64 + k];
    }
    for (int idx = tid; idx < 16 * 64; idx += 256) {
        int r = idx >> 6, k = idx & 63;
        Qsh[idx] = Qh[((size_t)mb * 128 + rc * 16 + r) * 64 + k];
    }
    __syncthreads();
    int rloc = tid >> 4, cg = tid & 15;
    float acc[8] = {};
    for (int k = 0; k < 64; ++k) {
        float qv = Qsh[rloc * 64 + k];
        const float* kr = &Ksh[k * 132 + cg * 8];
#pragma unroll
        for (int j = 0; j < 8; ++j) acc[j] += qv * kr[j];
    }
    float pm = -3.4e38f;
#pragma unroll
    for (int j = 0; j < 8; ++j) { acc[j] *= 0.125f; pm = fmaxf(pm, acc[j]); }
#pragma unroll
    for (int d = 1; d < 16; d <<= 1) pm = fmaxf(pm, __shfl_xor(pm, d, 64));
    int r = rc * 16 + rloc;
    if (cg == 0) rowmax[mb * 128 + r] = pm;
    float* dst = prior + ((size_t)mb * 128 + r) * 128 + cg * 8;
#pragma unroll
    for (int j = 0; j < 8; ++j) dst[j] = acc[j] - pm;
}

// ---------------- exact top-1024 threshold + list build (2-bit radix descent) --------
__global__ __launch_bounds__(1024)
void k_select(const float* __restrict__ prior, unsigned char* __restrict__ selmask,
              unsigned short* __restrict__ lists, int* __restrict__ counts,
              ushort* __restrict__ qorder) {
    const int mb = blockIdx.x, tid = threadIdx.x;
    const int ln = tid & 63;
    __shared__ int lc[16 * 3];                 // [level][field 3,2,1] counts
    __shared__ int cnt[128];
    if (tid < 48) lc[tid] = 0;
    if (tid < 128) cnt[tid] = 0;

    const int r = tid >> 3;                    // row (q-block) index, 8 threads/row
    const int cbase = (tid & 7) << 4;          // starting column
    uint key[16];
    const float4* P4 = (const float4*)(prior + (size_t)mb * 16384) + (tid << 2);
#pragma unroll
    for (int j4 = 0; j4 < 4; ++j4) {
        float4 v = P4[j4];
        float vv[4] = {v.x, v.y, v.z, v.w};
#pragma unroll
        for (int e = 0; e < 4; ++e) {
            int c = cbase + (j4 << 2) + e;
            float f = vv[e] + ((r - c <= 1 && c - r <= 1) ? 5e3f : 0.f);
            key[(j4 << 2) + e] = sortable(f);
        }
    }
    __syncthreads();                           // lc/cnt zeroed before use

    uint pfx = 0u;
    int k = 1024;
#pragma unroll
    for (int lvl = 0; lvl < 16; ++lvl) {
        const int sh = 30 - 2 * lvl;
        const uint maskA = (lvl == 0) ? 0u : (0xFFFFFFFFu << (sh + 2));
        int c3 = 0, c2 = 0, c1 = 0;
#pragma unroll
        for (int j = 0; j < 16; ++j) {
            uint x = key[j];
            bool m = ((x ^ pfx) & maskA) == 0u;
            uint f = (x >> sh) & 3u;
            c3 += (m && f == 3u);
            c2 += (m && f == 2u);
            c1 += (m && f == 1u);
        }
#pragma unroll
        for (int d = 1; d < 64; d <<= 1) {
            c3 += __shfl_xor(c3, d, 64);
            c2 += __shfl_xor(c2, d, 64);
            c1 += __shfl_xor(c1, d, 64);
        }
        if (ln == 0) {
            atomicAdd(&lc[lvl * 3 + 0], c3);
            atomicAdd(&lc[lvl * 3 + 1], c2);
            atomicAdd(&lc[lvl * 3 + 2], c1);
        }
        __syncthreads();
        const int C3 = lc[lvl * 3 + 0], C2 = lc[lvl * 3 + 1], C1 = lc[lvl * 3 + 2];
        uint choose;
        if (C3 >= k)                { choose = 3u; }
        else if (C3 + C2 >= k)      { choose = 2u; k -= C3; }
        else if (C3 + C2 + C1 >= k) { choose = 1u; k -= C3 + C2; }
        else                        { choose = 0u; k -= C3 + C2 + C1; }
        pfx |= choose << sh;
    }
    const uint T = pfx;                        // exact bit pattern of 1024th-largest prior

    uint packed[4] = {0u, 0u, 0u, 0u};
#pragma unroll
    for (int j = 0; j < 16; ++j) {
        if (key[j] >= T) {
            packed[j >> 2] |= 1u << ((j & 3) << 3);
            int pos = atomicAdd(&cnt[r], 1);
            lists[((size_t)mb * 128 + r) * 128 + pos] = (unsigned short)(cbase + j);
        }
    }
    uint4 pk;
    pk.x = packed[0]; pk.y = packed[1]; pk.z = packed[2]; pk.w = packed[3];
    *(uint4*)(selmask + (size_t)mb * 16384 + (size_t)tid * 16) = pk;
    __syncthreads();
    if (tid < 128) {
        const int myc = cnt[tid];
        counts[mb * 128 + tid] = myc;
        int rank = 0;
        for (int j = 0; j < 128; ++j) {        // broadcast LDS reads, O(128) per thread
            int cj = cnt[j];
            rank += (cj > myc) || (cj == myc && j < tid);
        }
        qorder[mb * 128 + rank] = (ushort)tid;
    }
}

// ---------------- high-res sparse attention + fused lowout + combine epilogue --------
// R16: k_lowout fused into the prologue. The 128-col non-selected loop (exactly
// k_lowout's body) runs while the first K/V prefetch is in flight; low_out lives in
// a register (lane d holds dim d) and reaches the epilogue via __shfl; low_norm is
// lane-uniform by construction. Removes a 3072-block kernel + launch gap + the
// low_out/low_norm HBM round-trip. Math bit-identical. R14 structure kept:
// XCD-locality work remap + setprio + R13 unroll-2 pipeline.
__global__ __launch_bounds__(64)
void k_high(const bf16* __restrict__ Qb, const bf16* __restrict__ Kb,
            const bf16* __restrict__ Vt, const int* __restrict__ counts,
            const unsigned short* __restrict__ lists, const ushort* __restrict__ qorder,
            const float* __restrict__ rowmax, const float* __restrict__ prior,
            const unsigned char* __restrict__ selmask, const float* __restrict__ tc,
            const float* __restrict__ Vh, const float* __restrict__ mask,
            float* __restrict__ out) {
    const int bid = blockIdx.x;
    const int work = ((bid & 7) * 384) + (bid >> 3);   // XCD-local mb grouping
    const int mb = work >> 7;
    const int q = qorder[mb * 128 + (work & 127)];
    const int lane = threadIdx.x, quad = lane >> 4, l16 = lane & 15;
    __shared__ bf16 Pa[32 * 40];
    __shared__ bf16 Pbs[32 * 40];

    const bf16* Qbase = Qb + ((size_t)mb * 4096 + q * 32) * 64;
    bf16x8 qf[2][2];
#pragma unroll
    for (int mt = 0; mt < 2; ++mt)
#pragma unroll
        for (int ks = 0; ks < 2; ++ks)
            qf[mt][ks] = *(const bf16x8*)(Qbase + (mt * 16 + l16) * 64 + ks * 32 + quad * 8);

    bf16x8 ones;
#pragma unroll
    for (int j = 0; j < 8; ++j) ones[j] = (bf16)1.0f;

    float mxl[2][4];                                   // per-lane raw logit max
    f32x4 o[2][4] = {};
    f32x4 lac[2] = {};                                 // row-sum accumulator (ones-MFMA)
#pragma unroll
    for (int mt = 0; mt < 2; ++mt)
#pragma unroll
        for (int r = 0; r < 4; ++r) mxl[mt][r] = -3.4e38f;

    int cntv = counts[mb * 128 + q];
    if (cntv > 128) cntv = 128;
    if (cntv < 1) cntv = 1;                            // diag band guarantees >=1
    const uint* lst32 = (const uint*)(lists + ((size_t)mb * 128 + q) * 128);

    const bf16* KB = Kb + (size_t)mb * 4096 * 64;
    const bf16* VB = Vt + (size_t)mb * 128 * 2048;

    int koff[2][2], voff[4];                           // per-lane elem offsets, reused
#pragma unroll
    for (int nt = 0; nt < 2; ++nt)
#pragma unroll
        for (int ks = 0; ks < 2; ++ks) koff[nt][ks] = (nt * 16 + l16) * 64 + ks * 32 + quad * 8;
#pragma unroll
    for (int nd = 0; nd < 4; ++nd) voff[nd] = (nd * 16 + l16) * 32 + quad * 8;

    bf16x8 kA[2][2], vA[4], kB[2][2], vB[4];
    {
        const uint pr = lst32[0];
        const int cA = __builtin_amdgcn_readfirstlane((int)(pr & 0xffffu));
        const bf16* kp = KB + (size_t)cA * 2048;
        const bf16* vp = VB + (size_t)cA * 2048;
#pragma unroll
        for (int nt = 0; nt < 2; ++nt)
#pragma unroll
            for (int ks = 0; ks < 2; ++ks) kA[nt][ks] = *(const bf16x8*)(kp + koff[nt][ks]);
#pragma unroll
        for (int nd = 0; nd < 4; ++nd) vA[nd] = *(const bf16x8*)(vp + voff[nd]);
        if (cntv > 1) {
            const int cB = __builtin_amdgcn_readfirstlane((int)(pr >> 16));
            const bf16* kp2 = KB + (size_t)cB * 2048;
            const bf16* vp2 = VB + (size_t)cB * 2048;
#pragma unroll
            for (int nt = 0; nt < 2; ++nt)
#pragma unroll
                for (int ks = 0; ks < 2; ++ks) kB[nt][ks] = *(const bf16x8*)(kp2 + koff[nt][ks]);
#pragma unroll
            for (int nd = 0; nd < 4; ++nd) vB[nd] = *(const bf16x8*)(vp2 + voff[nd]);
        }
    }

    // ---- fused low-res output over non-selected blocks (was k_lowout) ----
    // Runs while the K/V prefetch above is in flight. lane d accumulates dim d.
    float lo = 0.f, ln = 0.f;
    {
        const float* pn = prior + ((size_t)mb * 128 + q) * 128;
        const uint* sel32 = (const uint*)(selmask + ((size_t)mb * 128 + q) * 128);
        const float* tcb = tc + (mb / 12) * 128;
        const float* Vb = Vh + (size_t)mb * 128 * 64;
#pragma unroll 4
        for (int c = 0; c < 128; ++c) {
            if (!((sel32[c >> 2] >> ((c & 3) << 3)) & 1u)) {
                float w = __expf(pn[c]) * tcb[c];
                lo += w * Vb[c * 64 + lane];
                ln += w;
            }
        }
    }

    for (int i = 0; i < cntv; i += 2) {
        const bool hasB = (i + 1 < cntv);
        const bool hasAn = (i + 2 < cntv);
        const bool hasBn = (i + 3 < cntv);
        int cAn = 0, cBn = 0;
        if (hasAn) {
            const uint prn = lst32[(i >> 1) + 1];
            cAn = __builtin_amdgcn_readfirstlane((int)(prn & 0xffffu));
            cBn = __builtin_amdgcn_readfirstlane((int)(prn >> 16));
        }

        // ---- QK + exp/store, item A ----
        {
            f32x4 sf[2][2] = {};
            __builtin_amdgcn_s_setprio(1);
#pragma unroll
            for (int mt = 0; mt < 2; ++mt)
#pragma unroll
                for (int nt = 0; nt < 2; ++nt) {
                    sf[mt][nt] = __builtin_amdgcn_mfma_f32_16x16x32_bf16(qf[mt][0], kA[nt][0], sf[mt][nt], 0, 0, 0);
                    sf[mt][nt] = __builtin_amdgcn_mfma_f32_16x16x32_bf16(qf[mt][1], kA[nt][1], sf[mt][nt], 0, 0, 0);
                }
            __builtin_amdgcn_s_setprio(0);
#pragma unroll
            for (int mt = 0; mt < 2; ++mt)
#pragma unroll
                for (int r = 0; r < 4; ++r) {
                    mxl[mt][r] = fmaxf(mxl[mt][r], fmaxf(sf[mt][0][r], sf[mt][1][r]));
                    float e0, e1;
                    asm("v_exp_f32 %0, %1" : "=v"(e0) : "v"(sf[mt][0][r] * 0.18033688011112042f));
                    asm("v_exp_f32 %0, %1" : "=v"(e1) : "v"(sf[mt][1][r] * 0.18033688011112042f));
                    Pa[(mt * 16 + quad * 4 + r) * 40 + l16] = (bf16)e0;
                    Pa[(mt * 16 + quad * 4 + r) * 40 + 16 + l16] = (bf16)e1;
                }
        }
        // ---- QK + exp/store, item B ----
        if (hasB) {
            f32x4 sf[2][2] = {};
            __builtin_amdgcn_s_setprio(1);
#pragma unroll
            for (int mt = 0; mt < 2; ++mt)
#pragma unroll
                for (int nt = 0; nt < 2; ++nt) {
                    sf[mt][nt] = __builtin_amdgcn_mfma_f32_16x16x32_bf16(qf[mt][0], kB[nt][0], sf[mt][nt], 0, 0, 0);
                    sf[mt][nt] = __builtin_amdgcn_mfma_f32_16x16x32_bf16(qf[mt][1], kB[nt][1], sf[mt][nt], 0, 0, 0);
                }
            __builtin_amdgcn_s_setprio(0);
#pragma unroll
            for (int mt = 0; mt < 2; ++mt)
#pragma unroll
                for (int r = 0; r < 4; ++r) {
                    mxl[mt][r] = fmaxf(mxl[mt][r], fmaxf(sf[mt][0][r], sf[mt][1][r]));
                    float e0, e1;
                    asm("v_exp_f32 %0, %1" : "=v"(e0) : "v"(sf[mt][0][r] * 0.18033688011112042f));
                    asm("v_exp_f32 %0, %1" : "=v"(e1) : "v"(sf[mt][1][r] * 0.18033688011112042f));
                    Pbs[(mt * 16 + quad * 4 + r) * 40 + l16] = (bf16)e0;
                    Pbs[(mt * 16 + quad * 4 + r) * 40 + 16 + l16] = (bf16)e1;
                }
        }

        // K prefetch for next pair (kA/kB now dead)
        if (hasAn) {
            const bf16* kp = KB + (size_t)cAn * 2048;
#pragma unroll
            for (int nt = 0; nt < 2; ++nt)
#pragma unroll
                for (int ks = 0; ks < 2; ++ks) kA[nt][ks] = *(const bf16x8*)(kp + koff[nt][ks]);
        }
        if (hasBn) {
            const bf16* kp = KB + (size_t)cBn * 2048;
#pragma unroll
            for (int nt = 0; nt < 2; ++nt)
#pragma unroll
                for (int ks = 0; ks < 2; ++ks) kB[nt][ks] = *(const bf16x8*)(kp + koff[nt][ks]);
        }

        // single drain for both P slices (same-wave DS ops are in-order)
        asm volatile("s_waitcnt lgkmcnt(0)" ::: "memory");
        bf16x8 pa[2], pb[2];
#pragma unroll
        for (int mt = 0; mt < 2; ++mt)
            pa[mt] = *(const bf16x8*)&Pa[(mt * 16 + l16) * 40 + quad * 8];
        if (hasB) {
#pragma unroll
            for (int mt = 0; mt < 2; ++mt)
                pb[mt] = *(const bf16x8*)&Pbs[(mt * 16 + l16) * 40 + quad * 8];
        }
        __builtin_amdgcn_s_setprio(1);
#pragma unroll
        for (int mt = 0; mt < 2; ++mt) {
#pragma unroll
            for (int nd = 0; nd < 4; ++nd)
                o[mt][nd] = __builtin_amdgcn_mfma_f32_16x16x32_bf16(pa[mt], vA[nd], o[mt][nd], 0, 0, 0);
            lac[mt] = __builtin_amdgcn_mfma_f32_16x16x32_bf16(pa[mt], ones, lac[mt], 0, 0, 0);
        }
        if (hasB) {
#pragma unroll
            for (int mt = 0; mt < 2; ++mt) {
#pragma unroll
                for (int nd = 0; nd < 4; ++nd)
                    o[mt][nd] = __builtin_amdgcn_mfma_f32_16x16x32_bf16(pb[mt], vB[nd], o[mt][nd], 0, 0, 0);
                lac[mt] = __builtin_amdgcn_mfma_f32_16x16x32_bf16(pb[mt], ones, lac[mt], 0, 0, 0);
            }
        }
        __builtin_amdgcn_s_setprio(0);

        // V prefetch for next pair (vA/vB now dead)
        if (hasAn) {
            const bf16* vp = VB + (size_t)cAn * 2048;
#pragma unroll
            for (int nd = 0; nd < 4; ++nd) vA[nd] = *(const bf16x8*)(vp + voff[nd]);
        }
        if (hasBn) {
            const bf16* vp = VB + (size_t)cBn * 2048;
#pragma unroll
            for (int nd = 0; nd < 4; ++nd) vB[nd] = *(const bf16x8*)(vp + voff[nd]);
        }
    }

    // one-time 16-lane max reduction (raw logits; *0.125 afterwards is exact)
#pragma unroll
    for (int d = 1; d < 16; d <<= 1)
#pragma unroll
        for (int mt = 0; mt < 2; ++mt)
#pragma unroll
            for (int r = 0; r < 4; ++r)
                mxl[mt][r] = fmaxf(mxl[mt][r], __shfl_xor(mxl[mt][r], d, 64));

    // ---- fused combine epilogue (shift folded into hcf; LO via shfl, ln uniform) ----
    const int b = mb / 12, h = mb - b * 12;
    const float rm = rowmax[mb * 128 + q];
#pragma unroll
    for (int mt = 0; mt < 2; ++mt)
#pragma unroll
        for (int r = 0; r < 4; ++r) {
            const int s = q * 32 + mt * 16 + quad * 4 + r;
            const float mv = fmaxf(mxl[mt][r] * 0.125f, -1e6f);
            const float hn = lac[mt][r];
            const float mk = mask[(b << 12) + s];
            const float lcr = (rm - mv) * mk;
            const float lcf = __expf(fminf(lcr, 0.f));
            const float hcf = __expf(-mv - fmaxf(lcr, 0.f));   // exp(-mv)*ref_hcf
            const float den = 1.0f / (hn * hcf + ln * lcf + 1e-6f);
            float* op = out + ((size_t)(b * 4096 + s)) * 768 + h * 64;
#pragma unroll
            for (int nd = 0; nd < 4; ++nd) {
                const int d = nd * 16 + l16;
                const float LOd = __shfl(lo, d, 64);
                op[d] = (o[mt][nd][r] * hcf + LOd * lcf) * den;
            }
        }
}

extern "C" void kernel_launch(void* const* d_in, const int* in_sizes, int n_in,
                              void* d_out, int out_size, void* d_ws, size_t ws_size,
                              hipStream_t stream) {
    (void)in_sizes; (void)n_in; (void)out_size; (void)ws_size;
    const float* X    = (const float*)d_in[0];
    const float* mask = (const float*)d_in[1];
    const float* Wq   = (const float*)d_in[2];
    const float* bq   = (const float*)d_in[3];
    const float* Wk   = (const float*)d_in[4];
    const float* bk   = (const float*)d_in[5];
    const float* Wv   = (const float*)d_in[6];
    const float* bv   = (const float*)d_in[7];
    float* out = (float*)d_out;

    char* ws = (char*)d_ws;
    size_t off = 0;
    auto alloc = [&](size_t bytes) -> void* {
        off = (off + 255) & ~(size_t)255;
        void* p = ws + off;
        off += bytes;
        return p;
    };
    bf16* Xb  = (bf16*)alloc((size_t)8192 * 768 * 2);
    bf16* Wb  = (bf16*)alloc((size_t)2304 * 768 * 2);
    bf16* Qb  = (bf16*)alloc((size_t)24 * 4096 * 64 * 2);
    bf16* Kb  = (bf16*)alloc((size_t)24 * 4096 * 64 * 2);
    bf16* Vt  = (bf16*)alloc((size_t)24 * 4096 * 64 * 2);
    float* Xh = (float*)alloc((size_t)256 * 768 * 4);
    float* tc = (float*)alloc(256 * 4);
    float* Qh = (float*)alloc((size_t)24 * 128 * 64 * 4);
    float* Kh = (float*)alloc((size_t)24 * 128 * 64 * 4);
    float* Vh = (float*)alloc((size_t)24 * 128 * 64 * 4);
    float* prior = (float*)alloc((size_t)24 * 16384 * 4);
    float* rowmax = (float*)alloc(24 * 128 * 4);
    unsigned char* selmask = (unsigned char*)alloc((size_t)24 * 16384);
    unsigned short* lists = (unsigned short*)alloc((size_t)24 * 128 * 128 * 2);
    int* counts = (int*)alloc(24 * 128 * 4);
    ushort* qorder = (ushort*)alloc(24 * 128 * 2);
    float* partial   = (float*)alloc((size_t)7 * 589824 * 4);   // k-split partials, 16.5 MB

    k_prep<<<2496, 256, 0, stream>>>(X, mask, Wq, Wk, Wv, Xb, Xh, tc, Wb);
    k_gemm_qkv<<<dim3(64, 18), 256, 0, stream>>>(Xb, Wb, bq, bk, bv, mask, Qb, Kb, Vt);
    k_lowres_p<<<dim3(18, 2, 7), 256, 0, stream>>>(Xh, Wq, Wk, Wv, partial);
    k_lowfin<<<dim3(9, 256), 256, 0, stream>>>(partial, tc, bq, bk, bv, Qh, Kh, Vh);
    k_lowlogit<<<dim3(24, 8), 256, 0, stream>>>(Qh, Kh, prior, rowmax);
    k_select<<<24, 1024, 0, stream>>>(prior, selmask, lists, counts, qorder);
    k_high<<<3072, 64, 0, stream>>>(Qb, Kb, Vt, counts, lists, qorder, rowmax, prior,
                                    selmask, tc, Vh, mask, out);
}

// Round 13
// 244.144 us; speedup vs baseline: 1.1567x; 1.0667x over previous
//
#include <hip/hip_runtime.h>

typedef __bf16 bf16;
typedef float f32x4 __attribute__((ext_vector_type(4)));
typedef bf16 bf16x8 __attribute__((ext_vector_type(8)));
typedef bf16 bf16x4 __attribute__((ext_vector_type(4)));
typedef unsigned int uint;
typedef unsigned short ushort;

// Problem constants: B=2 S=4096 D=768 H=12 HD=64 BLK=32 NBR=128 MB=24 NUM_BLOCK=1024 DIAG_N=3

__device__ __forceinline__ void llds16(const bf16* g, bf16* l) {
    __builtin_amdgcn_global_load_lds((const __attribute__((address_space(1))) uint*)g,
                                     (__attribute__((address_space(3))) uint*)l, 16, 0, 0);
}

__device__ __forceinline__ uint sortable(float f) {
    uint u = __float_as_uint(f);
    return u ^ (uint)(((int)u >> 31) | 0x80000000);
}

// ---------------- fused prep: X->bf16 + masked block sums + token counts + W->bf16 ----
__global__ __launch_bounds__(256)
void k_prep(const float* __restrict__ X, const float* __restrict__ mask,
            const float* __restrict__ Wq, const float* __restrict__ Wk,
            const float* __restrict__ Wv,
            bf16* __restrict__ Xb, float* __restrict__ Xh, float* __restrict__ tc,
            bf16* __restrict__ Wb) {
    const int p = blockIdx.x;
    const int t = threadIdx.x;
    if (p >= 768) {                             // ---- W conversion part (1728 blocks) ----
        int i = (p - 768) * 256 + t;            // over 2304*768/4
        if (i >= 442368) return;
        int n = (i << 2) / 768;
        int k = (i << 2) % 768;
        const float* W = n < 768 ? Wq : (n < 1536 ? Wk : Wv);
        int nn = n - (n < 768 ? 0 : (n < 1536 ? 768 : 1536));
        float4 f = *(const float4*)(W + (size_t)nn * 768 + k);
        bf16x4 o = {(bf16)f.x, (bf16)f.y, (bf16)f.z, (bf16)f.w};
        ((bf16x4*)Wb)[i] = o;
        return;
    }
    const int row = p % 256;                    // b*128 + nbr
    const int g = p / 256;                      // colgroup 0..2
    const int b = row >> 7, nbr = row & 127;
    const int c = t & 63;                       // col within group
    const int tq = t >> 6;                      // token quarter 0..3
    const int c4 = g * 64 + c;                  // float4 column 0..191
    const size_t base = (size_t)(b * 4096 + nbr * 32) * 768;
    const float4* xp = (const float4*)(X + base) + c4;
    bf16x4* xbp = (bf16x4*)(Xb + base) + c4;
    const float* mp = mask + b * 4096 + nbr * 32;
    __shared__ float4 red[4][64];
    __shared__ float tcr[4];
    float4 s = {0.f, 0.f, 0.f, 0.f};
    float tcs = 0.f;
#pragma unroll
    for (int j = 0; j < 8; ++j) {
        const int tok = tq * 8 + j;
        float4 v = xp[(size_t)tok * 192];
        float m = mp[tok];
        s.x += v.x * m; s.y += v.y * m; s.z += v.z * m; s.w += v.w * m;
        tcs += m;
        bf16x4 o = {(bf16)v.x, (bf16)v.y, (bf16)v.z, (bf16)v.w};
        xbp[(size_t)tok * 192] = o;
    }
    red[tq][c] = s;
    if (c == 0) tcr[tq] = tcs;
    __syncthreads();
    if (tq == 0) {
        float4 a = red[0][c], b2 = red[1][c], c2 = red[2][c], d2 = red[3][c];
        float4 o = {a.x + b2.x + c2.x + d2.x, a.y + b2.y + c2.y + d2.y,
                    a.z + b2.z + c2.z + d2.z, a.w + b2.w + c2.w + d2.w};
        ((float4*)(Xh + (size_t)row * 768))[c4] = o;
        if (c == 0 && g == 0) tc[row] = tcr[0] + tcr[1] + tcr[2] + tcr[3];
    }
}

// ---------------- QKV projection GEMM (bf16 MFMA, 128x128 tile, BK=64, XOR swizzle) ----
// R8-proven K-loop + R11 coalesced LDS-transposed epilogue (43.7us).
__global__ __launch_bounds__(256, 4)
void k_gemm_qkv(const bf16* __restrict__ Xb, const bf16* __restrict__ Wb,
                const float* __restrict__ bq, const float* __restrict__ bk,
                const float* __restrict__ bv, const float* __restrict__ mask,
                bf16* __restrict__ Qb, bf16* __restrict__ Kb, bf16* __restrict__ Vt) {
    __shared__ bf16 smem[17408];                 // K-loop: As[0..8192) Bs[8192..16384)
    bf16* As = smem;                             // epilogue: C tile [128][136]
    bf16* Bs = smem + 8192;
    const int tid = threadIdx.x;
    const int wave = tid >> 6, lane = tid & 63;
    const int quad = lane >> 4, l16 = lane & 15;
    const int wr = wave >> 1, wc = wave & 1;
    const int m0 = blockIdx.x * 128, n0 = blockIdx.y * 128;
    const int srow = lane >> 3;                              // row within 8-row chunk
    const int sgcol = (((lane & 7) ^ (srow & 7)) << 3);      // swizzled source col

    f32x4 acc[4][4] = {};

    for (int k0 = 0; k0 < 768; k0 += 64) {
        __syncthreads();
#pragma unroll
        for (int it = 0; it < 4; ++it) {
            int R = wave * 32 + it * 8;
            llds16(Xb + (size_t)(m0 + R + srow) * 768 + k0 + sgcol, &As[R * 64]);
            llds16(Wb + (size_t)(n0 + R + srow) * 768 + k0 + sgcol, &Bs[R * 64]);
        }
        __syncthreads();
#pragma unroll
        for (int ks = 0; ks < 2; ++ks) {
            const int pg = ((ks * 4 + quad) ^ (l16 & 7)) << 3;  // physical group offset
            bf16x8 a[4], b[4];
#pragma unroll
            for (int i = 0; i < 4; ++i)
                a[i] = *(const bf16x8*)&As[(wr * 64 + i * 16 + l16) * 64 + pg];
#pragma unroll
            for (int i = 0; i < 4; ++i)
                b[i] = *(const bf16x8*)&Bs[(wc * 64 + i * 16 + l16) * 64 + pg];
#pragma unroll
            for (int i = 0; i < 4; ++i)
#pragma unroll
                for (int j = 0; j < 4; ++j)
                    acc[i][j] = __builtin_amdgcn_mfma_f32_16x16x32_bf16(a[i], b[j], acc[i][j], 0, 0, 0);
        }
    }

    const int which = n0 / 768;                       // uniform per block
    const float* bias = which == 0 ? bq : (which == 1 ? bk : bv);

    __syncthreads();                                  // K-loop LDS reads done
    // deposit quadrant into LDS (Q/K: [s][col] ; V: [col(d)][s]), stride 136
#pragma unroll
    for (int i = 0; i < 4; ++i) {
        const int rloc0 = wr * 64 + i * 16 + quad * 4;
#pragma unroll
        for (int j = 0; j < 4; ++j) {
            const int cloc = wc * 64 + j * 16 + l16;
            const int hcol = n0 - which * 768 + cloc;
            const float bv_ = bias[hcol];
#pragma unroll
            for (int r = 0; r < 4; ++r) {
                const int rloc = rloc0 + r;
                const int mm = m0 + rloc;
                const int bidx = mm >> 12, s = mm & 4095;
                const float y = (acc[i][j][r] + bv_) * mask[(bidx << 12) + s];
                if (which == 2) smem[cloc * 136 + rloc] = (bf16)y;
                else            smem[rloc * 136 + cloc] = (bf16)y;
            }
        }
    }
    __syncthreads();
    // coalesced read-out: 2048 x 16B chunks, 8 per thread
    if (which < 2) {
        bf16* dst = which == 0 ? Qb : Kb;
#pragma unroll
        for (int it = 0; it < 8; ++it) {
            const int gidx = it * 256 + tid;
            const int sr = gidx >> 4, chunk = gidx & 15;
            const int mm = m0 + sr;
            const int bidx = mm >> 12, s = mm & 4095;
            const int hcol = n0 - which * 768 + chunk * 8;
            const int h = hcol >> 6, d0 = hcol & 63;
            bf16x8 v = *(const bf16x8*)&smem[sr * 136 + chunk * 8];
            *(bf16x8*)(dst + ((((size_t)(bidx * 12 + h)) << 12) + s) * 64 + d0) = v;
        }
    } else {
#pragma unroll
        for (int it = 0; it < 8; ++it) {
            const int gidx = it * 256 + tid;
            const int drow = gidx >> 4, chunk = gidx & 15;
            const int s0 = chunk * 8;
            const int mm = m0 + s0;
            const int bidx = mm >> 12, s = mm & 4095;     // s..s+7 within one 32-block
            const int hcol = n0 - 1536 + drow;
            const int h = hcol >> 6, dd = hcol & 63;
            bf16x8 v = *(const bf16x8*)&smem[drow * 136 + s0];
            *(bf16x8*)(Vt + ((((size_t)(bidx * 12 + h)) * 128 + (s >> 5)) * 64 + dd) * 32 + (s & 31)) = v;
        }
    }
}

// ---------------- exact f32 low-res projections, register-tiled with k-split ----------
__global__ __launch_bounds__(256)
void k_lowres_p(const float* __restrict__ Xh,
                const float* __restrict__ Wq, const float* __restrict__ Wk,
                const float* __restrict__ Wv, float* __restrict__ partial) {
    const int nb = blockIdx.x;                  // 0..17 : 128-col tile of [q|k|v] weights
    const int rowbase = blockIdx.y * 128;       // 0 or 128
    const int bz = blockIdx.z;                  // k-chunk 0..6
    const int kb = bz * 112;
    const int klen = (bz == 6) ? 96 : 112;
    const int t = threadIdx.x;

    __shared__ float As[16 * 132];              // [k][row], +4 pad
    __shared__ float Bs[16 * 132];              // [k][col], +4 pad

    const int which = nb / 6;
    const float* Wsel = which == 0 ? Wq : (which == 1 ? Wk : Wv);
    const float* Wbase = Wsel + (size_t)((nb % 6) * 128) * 768;

    const int sr = t >> 2;                      // staging row/col (+64*i)
    const int skq = t & 3;                      // staging k-quad
    const int tr = t >> 4, tc2 = t & 15;
    const int r0 = tr * 8, c0 = tc2 * 8;

    float acc[8][8] = {};
    float4 va[2], vb[2];
    const int stages = klen >> 4;

#pragma unroll
    for (int i = 0; i < 2; ++i) {               // prologue: stage-0 loads
        va[i] = *(const float4*)(Xh + (size_t)(rowbase + sr + 64 * i) * 768 + kb + skq * 4);
        vb[i] = *(const float4*)(Wbase + (size_t)(sr + 64 * i) * 768 + kb + skq * 4);
    }

    for (int s = 0; s < stages; ++s) {
        __syncthreads();
#pragma unroll
        for (int i = 0; i < 2; ++i) {           // transposed LDS store (2-way bank, free)
            const int r = sr + 64 * i;
            As[(skq * 4 + 0) * 132 + r] = va[i].x;
            As[(skq * 4 + 1) * 132 + r] = va[i].y;
            As[(skq * 4 + 2) * 132 + r] = va[i].z;
            As[(skq * 4 + 3) * 132 + r] = va[i].w;
            Bs[(skq * 4 + 0) * 132 + r] = vb[i].x;
            Bs[(skq * 4 + 1) * 132 + r] = vb[i].y;
            Bs[(skq * 4 + 2) * 132 + r] = vb[i].z;
            Bs[(skq * 4 + 3) * 132 + r] = vb[i].w;
        }
        if (s + 1 < stages) {                   // prefetch next stage (hides under compute)
            const int kc = kb + (s + 1) * 16;
#pragma unroll
            for (int i = 0; i < 2; ++i) {
                va[i] = *(const float4*)(Xh + (size_t)(rowbase + sr + 64 * i) * 768 + kc + skq * 4);
                vb[i] = *(const float4*)(Wbase + (size_t)(sr + 64 * i) * 768 + kc + skq * 4);
            }
        }
        __syncthreads();
#pragma unroll
        for (int k = 0; k < 16; ++k) {
            float4 a0 = *(const float4*)&As[k * 132 + r0];
            float4 a1 = *(const float4*)&As[k * 132 + r0 + 4];
            float4 b0 = *(const float4*)&Bs[k * 132 + c0];
            float4 b1 = *(const float4*)&Bs[k * 132 + c0 + 4];
            float av[8] = {a0.x, a0.y, a0.z, a0.w, a1.x, a1.y, a1.z, a1.w};
            float bv[8] = {b0.x, b0.y, b0.z, b0.w, b1.x, b1.y, b1.z, b1.w};
#pragma unroll
            for (int i = 0; i < 8; ++i)
#pragma unroll
                for (int j = 0; j < 8; ++j)
                    acc[i][j] += av[i] * bv[j];
        }
    }

    float* pp = partial + (size_t)bz * 589824 + (size_t)(rowbase + r0) * 2304 + nb * 128 + c0;
#pragma unroll
    for (int i = 0; i < 8; ++i) {
        float4 s0 = {acc[i][0], acc[i][1], acc[i][2], acc[i][3]};
        float4 s1 = {acc[i][4], acc[i][5], acc[i][6], acc[i][7]};
        *(float4*)(pp + (size_t)i * 2304) = s0;
        *(float4*)(pp + (size_t)i * 2304 + 4) = s1;
    }
}

// ---------------- reduce k-split partials + bias + token-count div + scatter ----------
__global__ __launch_bounds__(256)
void k_lowfin(const float* __restrict__ partial, const float* __restrict__ tc,
              const float* __restrict__ bq, const float* __restrict__ bk,
              const float* __restrict__ bv,
              float* __restrict__ Qh, float* __restrict__ Kh, float* __restrict__ Vh) {
    const int gx = blockIdx.x;                  // 0..8 : 256-col group
    const int row = blockIdx.y;                 // 0..255
    const int t = threadIdx.x;
    const int gcol = gx * 256 + t;
    float s = 0.f;
#pragma unroll
    for (int ch = 0; ch < 7; ++ch)
        s += partial[(size_t)ch * 589824 + (size_t)row * 2304 + gcol];
    const int which = gx / 3;
    const int wcol = (gx % 3) * 256 + t;
    const float* bias = which == 0 ? bq : (which == 1 ? bk : bv);
    const float tcv = tc[row];
    const float val = (s + tcv * bias[wcol]) / (tcv + 1e-6f);
    const int b = row >> 7, nbr = row & 127;
    const int h = wcol >> 6, d = wcol & 63;
    float* dst = which == 0 ? Qh : (which == 1 ? Kh : Vh);
    dst[(((size_t)(b * 12 + h)) * 128 + nbr) * 64 + d] = val;
}

// ---------------- low-res logits + row max + FULL low-res attention (R17) -------------
// R17: also computes full_lo[q][d] = sum_c exp(prior)*tc[c]*Vh[c][d] and full_ln[q]
// (no selmask needed). k_high subtracts the selected terms per list item, so the
// 128-iter serial lowout loop leaves k_high's critical path entirely.
__global__ __launch_bounds__(256)
void k_lowlogit(const float* __restrict__ Qh, const float* __restrict__ Kh,
                const float* __restrict__ tc, const float* __restrict__ Vh,
                float* __restrict__ prior, float* __restrict__ rowmax,
                float* __restrict__ full_lo, float* __restrict__ full_ln) {
    int mb = blockIdx.x, rc = blockIdx.y;             // grid (24, 8)
    int tid = threadIdx.x;
    __shared__ float Ksh[64 * 132];                   // [k][c] padded; reused as Vsh[128][66]
    __shared__ float Qsh[16 * 64];
    __shared__ float Wsh[16 * 132];                   // weights w per (qloc, c)
    for (int idx = tid; idx < 128 * 64; idx += 256) {
        int c = idx >> 6, k = idx & 63;
        Ksh[k * 132 + c] = Kh[((size_t)mb * 128 + c) * 64 + k];
    }
    for (int idx = tid; idx < 16 * 64; idx += 256) {
        int r = idx >> 6, k = idx & 63;
        Qsh[idx] = Qh[((size_t)mb * 128 + rc * 16 + r) * 64 + k];
    }
    __syncthreads();
    int rloc = tid >> 4, cg = tid & 15;
    float acc[8] = {};
    for (int k = 0; k < 64; ++k) {
        float qv = Qsh[rloc * 64 + k];
        const float* kr = &Ksh[k * 132 + cg * 8];
#pragma unroll
        for (int j = 0; j < 8; ++j) acc[j] += qv * kr[j];
    }
    float pm = -3.4e38f;
#pragma unroll
    for (int j = 0; j < 8; ++j) { acc[j] *= 0.125f; pm = fmaxf(pm, acc[j]); }
#pragma unroll
    for (int d = 1; d < 16; d <<= 1) pm = fmaxf(pm, __shfl_xor(pm, d, 64));
    int r = rc * 16 + rloc;
    if (cg == 0) rowmax[mb * 128 + r] = pm;
    float* dst = prior + ((size_t)mb * 128 + r) * 128 + cg * 8;
    const float* tcb = tc + (mb / 12) * 128;
    float lnv = 0.f;
#pragma unroll
    for (int j = 0; j < 8; ++j) {
        const float pv = acc[j] - pm;
        dst[j] = pv;
        const float w = __expf(pv) * tcb[cg * 8 + j];
        Wsh[rloc * 132 + cg * 8 + j] = w;
        lnv += w;
    }
#pragma unroll
    for (int d = 1; d < 16; d <<= 1) lnv += __shfl_xor(lnv, d, 64);
    if (cg == 0) full_ln[mb * 128 + r] = lnv;
    __syncthreads();                                  // all Ksh reads done; Wsh complete
    float* Vsh = Ksh;                                 // 128*66 = 8448 floats, exact reuse
    for (int idx = tid; idx < 128 * 64; idx += 256) {
        int c = idx >> 6, d = idx & 63;
        Vsh[c * 66 + d] = Vh[((size_t)mb * 128 + c) * 64 + d];
    }
    __syncthreads();
    // full_lo: 16q x 64d outputs, 4 per thread
    const int d = tid & 63, grp = tid >> 6;
    float o0 = 0.f, o1 = 0.f, o2 = 0.f, o3 = 0.f;
    const float* W0 = &Wsh[(grp * 4 + 0) * 132];
    const float* W1 = &Wsh[(grp * 4 + 1) * 132];
    const float* W2 = &Wsh[(grp * 4 + 2) * 132];
    const float* W3 = &Wsh[(grp * 4 + 3) * 132];
    for (int c = 0; c < 128; ++c) {
        const float v = Vsh[c * 66 + d];
        o0 += W0[c] * v; o1 += W1[c] * v; o2 += W2[c] * v; o3 += W3[c] * v;
    }
    const size_t qb = (size_t)mb * 128 + rc * 16 + grp * 4;
    full_lo[(qb + 0) * 64 + d] = o0;
    full_lo[(qb + 1) * 64 + d] = o1;
    full_lo[(qb + 2) * 64 + d] = o2;
    full_lo[(qb + 3) * 64 + d] = o3;
}

// ---------------- exact top-1024 threshold + list build (2-bit radix descent) --------
__global__ __launch_bounds__(1024)
void k_select(const float* __restrict__ prior, unsigned char* __restrict__ selmask,
              unsigned short* __restrict__ lists, int* __restrict__ counts,
              ushort* __restrict__ qorder) {
    const int mb = blockIdx.x, tid = threadIdx.x;
    const int ln = tid & 63;
    __shared__ int lc[16 * 3];                 // [level][field 3,2,1] counts
    __shared__ int cnt[128];
    if (tid < 48) lc[tid] = 0;
    if (tid < 128) cnt[tid] = 0;

    const int r = tid >> 3;                    // row (q-block) index, 8 threads/row
    const int cbase = (tid & 7) << 4;          // starting column
    uint key[16];
    const float4* P4 = (const float4*)(prior + (size_t)mb * 16384) + (tid << 2);
#pragma unroll
    for (int j4 = 0; j4 < 4; ++j4) {
        float4 v = P4[j4];
        float vv[4] = {v.x, v.y, v.z, v.w};
#pragma unroll
        for (int e = 0; e < 4; ++e) {
            int c = cbase + (j4 << 2) + e;
            float f = vv[e] + ((r - c <= 1 && c - r <= 1) ? 5e3f : 0.f);
            key[(j4 << 2) + e] = sortable(f);
        }
    }
    __syncthreads();                           // lc/cnt zeroed before use

    uint pfx = 0u;
    int k = 1024;
#pragma unroll
    for (int lvl = 0; lvl < 16; ++lvl) {
        const int sh = 30 - 2 * lvl;
        const uint maskA = (lvl == 0) ? 0u : (0xFFFFFFFFu << (sh + 2));
        int c3 = 0, c2 = 0, c1 = 0;
#pragma unroll
        for (int j = 0; j < 16; ++j) {
            uint x = key[j];
            bool m = ((x ^ pfx) & maskA) == 0u;
            uint f = (x >> sh) & 3u;
            c3 += (m && f == 3u);
            c2 += (m && f == 2u);
            c1 += (m && f == 1u);
        }
#pragma unroll
        for (int d = 1; d < 64; d <<= 1) {
            c3 += __shfl_xor(c3, d, 64);
            c2 += __shfl_xor(c2, d, 64);
            c1 += __shfl_xor(c1, d, 64);
        }
        if (ln == 0) {
            atomicAdd(&lc[lvl * 3 + 0], c3);
            atomicAdd(&lc[lvl * 3 + 1], c2);
            atomicAdd(&lc[lvl * 3 + 2], c1);
        }
        __syncthreads();
        const int C3 = lc[lvl * 3 + 0], C2 = lc[lvl * 3 + 1], C1 = lc[lvl * 3 + 2];
        uint choose;
        if (C3 >= k)                { choose = 3u; }
        else if (C3 + C2 >= k)      { choose = 2u; k -= C3; }
        else if (C3 + C2 + C1 >= k) { choose = 1u; k -= C3 + C2; }
        else                        { choose = 0u; k -= C3 + C2 + C1; }
        pfx |= choose << sh;
    }
    const uint T = pfx;                        // exact bit pattern of 1024th-largest prior

    uint packed[4] = {0u, 0u, 0u, 0u};
#pragma unroll
    for (int j = 0; j < 16; ++j) {
        if (key[j] >= T) {
            packed[j >> 2] |= 1u << ((j & 3) << 3);
            int pos = atomicAdd(&cnt[r], 1);
            lists[((size_t)mb * 128 + r) * 128 + pos] = (unsigned short)(cbase + j);
        }
    }
    uint4 pk;
    pk.x = packed[0]; pk.y = packed[1]; pk.z = packed[2]; pk.w = packed[3];
    *(uint4*)(selmask + (size_t)mb * 16384 + (size_t)tid * 16) = pk;
    __syncthreads();
    if (tid < 128) {
        const int myc = cnt[tid];
        counts[mb * 128 + tid] = myc;
        int rank = 0;
        for (int j = 0; j < 128; ++j) {        // broadcast LDS reads, O(128) per thread
            int cj = cnt[j];
            rank += (cj > myc) || (cj == myc && j < tid);
        }
        qorder[mb * 128 + rank] = (ushort)tid;
    }
}

// ---------------- high-res sparse attention + subtract-selected lowout + combine -----
// R17: lo/ln start from full_lo/full_ln (computed in k_lowlogit); per list item the
// selected term w*Vh[c] is subtracted (6 VALU + 2 L2-hot loads, hidden under MFMA).
// The 128-iter serial prologue (R16's +27us) is gone. R14 structure kept.
__global__ __launch_bounds__(64)
void k_high(const bf16* __restrict__ Qb, const bf16* __restrict__ Kb,
            const bf16* __restrict__ Vt, const int* __restrict__ counts,
            const unsigned short* __restrict__ lists, const ushort* __restrict__ qorder,
            const float* __restrict__ rowmax, const float* __restrict__ prior,
            const float* __restrict__ tc, const float* __restrict__ Vh,
            const float* __restrict__ full_lo, const float* __restrict__ full_ln,
            const float* __restrict__ mask, float* __restrict__ out) {
    const int bid = blockIdx.x;
    const int work = ((bid & 7) * 384) + (bid >> 3);   // XCD-local mb grouping
    const int mb = work >> 7;
    const int q = qorder[mb * 128 + (work & 127)];
    const int lane = threadIdx.x, quad = lane >> 4, l16 = lane & 15;
    __shared__ bf16 Pa[32 * 40];
    __shared__ bf16 Pbs[32 * 40];

    const bf16* Qbase = Qb + ((size_t)mb * 4096 + q * 32) * 64;
    bf16x8 qf[2][2];
#pragma unroll
    for (int mt = 0; mt < 2; ++mt)
#pragma unroll
        for (int ks = 0; ks < 2; ++ks)
            qf[mt][ks] = *(const bf16x8*)(Qbase + (mt * 16 + l16) * 64 + ks * 32 + quad * 8);

    bf16x8 ones;
#pragma unroll
    for (int j = 0; j < 8; ++j) ones[j] = (bf16)1.0f;

    float mxl[2][4];                                   // per-lane raw logit max
    f32x4 o[2][4] = {};
    f32x4 lac[2] = {};                                 // row-sum accumulator (ones-MFMA)
#pragma unroll
    for (int mt = 0; mt < 2; ++mt)
#pragma unroll
        for (int r = 0; r < 4; ++r) mxl[mt][r] = -3.4e38f;

    int cntv = counts[mb * 128 + q];
    if (cntv > 128) cntv = 128;
    if (cntv < 1) cntv = 1;                            // diag band guarantees >=1
    const uint* lst32 = (const uint*)(lists + ((size_t)mb * 128 + q) * 128);

    const bf16* KB = Kb + (size_t)mb * 4096 * 64;
    const bf16* VB = Vt + (size_t)mb * 128 * 2048;
    const float* pn = prior + ((size_t)mb * 128 + q) * 128;
    const float* tcb = tc + (mb / 12) * 128;
    const float* VhB = Vh + (size_t)mb * 128 * 64;

    int koff[2][2], voff[4];                           // per-lane elem offsets, reused
#pragma unroll
    for (int nt = 0; nt < 2; ++nt)
#pragma unroll
        for (int ks = 0; ks < 2; ++ks) koff[nt][ks] = (nt * 16 + l16) * 64 + ks * 32 + quad * 8;
#pragma unroll
    for (int nd = 0; nd < 4; ++nd) voff[nd] = (nd * 16 + l16) * 32 + quad * 8;

    // lo/ln start from the full low-res attention; selected terms subtracted in-loop
    float lo = full_lo[((size_t)mb * 128 + q) * 64 + lane];
    float ln = full_ln[mb * 128 + q];

    bf16x8 kA[2][2], vA[4], kB[2][2], vB[4];
    {
        const uint pr = lst32[0];
        const int cA = __builtin_amdgcn_readfirstlane((int)(pr & 0xffffu));
        const bf16* kp = KB + (size_t)cA * 2048;
        const bf16* vp = VB + (size_t)cA * 2048;
#pragma unroll
        for (int nt = 0; nt < 2; ++nt)
#pragma unroll
            for (int ks = 0; ks < 2; ++ks) kA[nt][ks] = *(const bf16x8*)(kp + koff[nt][ks]);
#pragma unroll
        for (int nd = 0; nd < 4; ++nd) vA[nd] = *(const bf16x8*)(vp + voff[nd]);
        if (cntv > 1) {
            const int cB = __builtin_amdgcn_readfirstlane((int)(pr >> 16));
            const bf16* kp2 = KB + (size_t)cB * 2048;
            const bf16* vp2 = VB + (size_t)cB * 2048;
#pragma unroll
            for (int nt = 0; nt < 2; ++nt)
#pragma unroll
                for (int ks = 0; ks < 2; ++ks) kB[nt][ks] = *(const bf16x8*)(kp2 + koff[nt][ks]);
#pragma unroll
            for (int nd = 0; nd < 4; ++nd) vB[nd] = *(const bf16x8*)(vp2 + voff[nd]);
        }
    }

    for (int i = 0; i < cntv; i += 2) {
        const bool hasB = (i + 1 < cntv);
        const bool hasAn = (i + 2 < cntv);
        const bool hasBn = (i + 3 < cntv);
        int cAn = 0, cBn = 0;
        if (hasAn) {
            const uint prn = lst32[(i >> 1) + 1];
            cAn = __builtin_amdgcn_readfirstlane((int)(prn & 0xffffu));
            cBn = __builtin_amdgcn_readfirstlane((int)(prn >> 16));
        }

        // ---- QK + exp/store, item A ----
        {
            f32x4 sf[2][2] = {};
            __builtin_amdgcn_s_setprio(1);
#pragma unroll
            for (int mt = 0; mt < 2; ++mt)
#pragma unroll
                for (int nt = 0; nt < 2; ++nt) {
                    sf[mt][nt] = __builtin_amdgcn_mfma_f32_16x16x32_bf16(qf[mt][0], kA[nt][0], sf[mt][nt], 0, 0, 0);
                    sf[mt][nt] = __builtin_amdgcn_mfma_f32_16x16x32_bf16(qf[mt][1], kA[nt][1], sf[mt][nt], 0, 0, 0);
                }
            __builtin_amdgcn_s_setprio(0);
#pragma unroll
            for (int mt = 0; mt < 2; ++mt)
#pragma unroll
                for (int r = 0; r < 4; ++r) {
                    mxl[mt][r] = fmaxf(mxl[mt][r], fmaxf(sf[mt][0][r], sf[mt][1][r]));
                    float e0, e1;
                    asm("v_exp_f32 %0, %1" : "=v"(e0) : "v"(sf[mt][0][r] * 0.18033688011112042f));
                    asm("v_exp_f32 %0, %1" : "=v"(e1) : "v"(sf[mt][1][r] * 0.18033688011112042f));
                    Pa[(mt * 16 + quad * 4 + r) * 40 + l16] = (bf16)e0;
                    Pa[(mt * 16 + quad * 4 + r) * 40 + 16 + l16] = (bf16)e1;
                }
        }
        // ---- QK + exp/store, item B ----
        if (hasB) {
            f32x4 sf[2][2] = {};
            __builtin_amdgcn_s_setprio(1);
#pragma unroll
            for (int mt = 0; mt < 2; ++mt)
#pragma unroll
                for (int nt = 0; nt < 2; ++nt) {
                    sf[mt][nt] = __builtin_amdgcn_mfma_f32_16x16x32_bf16(qf[mt][0], kB[nt][0], sf[mt][nt], 0, 0, 0);
                    sf[mt][nt] = __builtin_amdgcn_mfma_f32_16x16x32_bf16(qf[mt][1], kB[nt][1], sf[mt][nt], 0, 0, 0);
                }
            __builtin_amdgcn_s_setprio(0);
#pragma unroll
            for (int mt = 0; mt < 2; ++mt)
#pragma unroll
                for (int r = 0; r < 4; ++r) {
                    mxl[mt][r] = fmaxf(mxl[mt][r], fmaxf(sf[mt][0][r], sf[mt][1][r]));
                    float e0, e1;
                    asm("v_exp_f32 %0, %1" : "=v"(e0) : "v"(sf[mt][0][r] * 0.18033688011112042f));
                    asm("v_exp_f32 %0, %1" : "=v"(e1) : "v"(sf[mt][1][r] * 0.18033688011112042f));
                    Pbs[(mt * 16 + quad * 4 + r) * 40 + l16] = (bf16)e0;
                    Pbs[(mt * 16 + quad * 4 + r) * 40 + 16 + l16] = (bf16)e1;
                }
        }

        // K prefetch for next pair (kA/kB now dead)
        if (hasAn) {
            const bf16* kp = KB + (size_t)cAn * 2048;
#pragma unroll
            for (int nt = 0; nt < 2; ++nt)
#pragma unroll
                for (int ks = 0; ks < 2; ++ks) kA[nt][ks] = *(const bf16x8*)(kp + koff[nt][ks]);
        }
        if (hasBn) {
            const bf16* kp = KB + (size_t)cBn * 2048;
#pragma unroll
            for (int nt = 0; nt < 2; ++nt)
#pragma unroll
                for (int ks = 0; ks < 2; ++ks) kB[nt][ks] = *(const bf16x8*)(kp + koff[nt][ks]);
        }

        // subtract selected low-res terms for this pair (overlaps MFMA/LDS waits)
        {
            const uint prc = lst32[i >> 1];
            const int cAc = (int)(prc & 0xffffu);
            const float wA = __expf(pn[cAc]) * tcb[cAc];
            lo -= wA * VhB[cAc * 64 + lane];
            ln -= wA;
            if (hasB) {
                const int cBc = (int)(prc >> 16);
                const float wB = __expf(pn[cBc]) * tcb[cBc];
                lo -= wB * VhB[cBc * 64 + lane];
                ln -= wB;
            }
        }

        // single drain for both P slices (same-wave DS ops are in-order)
        asm volatile("s_waitcnt lgkmcnt(0)" ::: "memory");
        bf16x8 pa[2], pb[2];
#pragma unroll
        for (int mt = 0; mt < 2; ++mt)
            pa[mt] = *(const bf16x8*)&Pa[(mt * 16 + l16) * 40 + quad * 8];
        if (hasB) {
#pragma unroll
            for (int mt = 0; mt < 2; ++mt)
                pb[mt] = *(const bf16x8*)&Pbs[(mt * 16 + l16) * 40 + quad * 8];
        }
        __builtin_amdgcn_s_setprio(1);
#pragma unroll
        for (int mt = 0; mt < 2; ++mt) {
#pragma unroll
            for (int nd = 0; nd < 4; ++nd)
                o[mt][nd] = __builtin_amdgcn_mfma_f32_16x16x32_bf16(pa[mt], vA[nd], o[mt][nd], 0, 0, 0);
            lac[mt] = __builtin_amdgcn_mfma_f32_16x16x32_bf16(pa[mt], ones, lac[mt], 0, 0, 0);
        }
        if (hasB) {
#pragma unroll
            for (int mt = 0; mt < 2; ++mt) {
#pragma unroll
                for (int nd = 0; nd < 4; ++nd)
                    o[mt][nd] = __builtin_amdgcn_mfma_f32_16x16x32_bf16(pb[mt], vB[nd], o[mt][nd], 0, 0, 0);
                lac[mt] = __builtin_amdgcn_mfma_f32_16x16x32_bf16(pb[mt], ones, lac[mt], 0, 0, 0);
            }
        }
        __builtin_amdgcn_s_setprio(0);

        // V prefetch for next pair (vA/vB now dead)
        if (hasAn) {
            const bf16* vp = VB + (size_t)cAn * 2048;
#pragma unroll
            for (int nd = 0; nd < 4; ++nd) vA[nd] = *(const bf16x8*)(vp + voff[nd]);
        }
        if (hasBn) {
            const bf16* vp = VB + (size_t)cBn * 2048;
#pragma unroll
            for (int nd = 0; nd < 4; ++nd) vB[nd] = *(const bf16x8*)(vp + voff[nd]);
        }
    }

    // one-time 16-lane max reduction (raw logits; *0.125 afterwards is exact)
#pragma unroll
    for (int d = 1; d < 16; d <<= 1)
#pragma unroll
        for (int mt = 0; mt < 2; ++mt)
#pragma unroll
            for (int r = 0; r < 4; ++r)
                mxl[mt][r] = fmaxf(mxl[mt][r], __shfl_xor(mxl[mt][r], d, 64));

    // ---- fused combine epilogue (shift folded into hcf; LO via shfl, ln uniform) ----
    const int b = mb / 12, h = mb - b * 12;
    const float rm = rowmax[mb * 128 + q];
#pragma unroll
    for (int mt = 0; mt < 2; ++mt)
#pragma unroll
        for (int r = 0; r < 4; ++r) {
            const int s = q * 32 + mt * 16 + quad * 4 + r;
            const float mv = fmaxf(mxl[mt][r] * 0.125f, -1e6f);
            const float hn = lac[mt][r];
            const float mk = mask[(b << 12) + s];
            const float lcr = (rm - mv) * mk;
            const float lcf = __expf(fminf(lcr, 0.f));
            const float hcf = __expf(-mv - fmaxf(lcr, 0.f));   // exp(-mv)*ref_hcf
            const float den = 1.0f / (hn * hcf + ln * lcf + 1e-6f);
            float* op = out + ((size_t)(b * 4096 + s)) * 768 + h * 64;
#pragma unroll
            for (int nd = 0; nd < 4; ++nd) {
                const int d = nd * 16 + l16;
                const float LOd = __shfl(lo, d, 64);
                op[d] = (o[mt][nd][r] * hcf + LOd * lcf) * den;
            }
        }
}

extern "C" void kernel_launch(void* const* d_in, const int* in_sizes, int n_in,
                              void* d_out, int out_size, void* d_ws, size_t ws_size,
                              hipStream_t stream) {
    (void)in_sizes; (void)n_in; (void)out_size; (void)ws_size;
    const float* X    = (const float*)d_in[0];
    const float* mask = (const float*)d_in[1];
    const float* Wq   = (const float*)d_in[2];
    const float* bq   = (const float*)d_in[3];
    const float* Wk   = (const float*)d_in[4];
    const float* bk   = (const float*)d_in[5];
    const float* Wv   = (const float*)d_in[6];
    const float* bv   = (const float*)d_in[7];
    float* out = (float*)d_out;

    char* ws = (char*)d_ws;
    size_t off = 0;
    auto alloc = [&](size_t bytes) -> void* {
        off = (off + 255) & ~(size_t)255;
        void* p = ws + off;
        off += bytes;
        return p;
    };
    bf16* Xb  = (bf16*)alloc((size_t)8192 * 768 * 2);
    bf16* Wb  = (bf16*)alloc((size_t)2304 * 768 * 2);
    bf16* Qb  = (bf16*)alloc((size_t)24 * 4096 * 64 * 2);
    bf16* Kb  = (bf16*)alloc((size_t)24 * 4096 * 64 * 2);
    bf16* Vt  = (bf16*)alloc((size_t)24 * 4096 * 64 * 2);
    float* Xh = (float*)alloc((size_t)256 * 768 * 4);
    float* tc = (float*)alloc(256 * 4);
    float* Qh = (float*)alloc((size_t)24 * 128 * 64 * 4);
    float* Kh = (float*)alloc((size_t)24 * 128 * 64 * 4);
    float* Vh = (float*)alloc((size_t)24 * 128 * 64 * 4);
    float* prior = (float*)alloc((size_t)24 * 16384 * 4);
    float* rowmax = (float*)alloc(24 * 128 * 4);
    unsigned char* selmask = (unsigned char*)alloc((size_t)24 * 16384);
    unsigned short* lists = (unsigned short*)alloc((size_t)24 * 128 * 128 * 2);
    int* counts = (int*)alloc(24 * 128 * 4);
    ushort* qorder = (ushort*)alloc(24 * 128 * 2);
    float* full_lo = (float*)alloc((size_t)24 * 128 * 64 * 4);
    float* full_ln = (float*)alloc(24 * 128 * 4);
    float* partial   = (float*)alloc((size_t)7 * 589824 * 4);   // k-split partials, 16.5 MB

    k_prep<<<2496, 256, 0, stream>>>(X, mask, Wq, Wk, Wv, Xb, Xh, tc, Wb);
    k_gemm_qkv<<<dim3(64, 18), 256, 0, stream>>>(Xb, Wb, bq, bk, bv, mask, Qb, Kb, Vt);
    k_lowres_p<<<dim3(18, 2, 7), 256, 0, stream>>>(Xh, Wq, Wk, Wv, partial);
    k_lowfin<<<dim3(9, 256), 256, 0, stream>>>(partial, tc, bq, bk, bv, Qh, Kh, Vh);
    k_lowlogit<<<dim3(24, 8), 256, 0, stream>>>(Qh, Kh, tc, Vh, prior, rowmax,
                                                full_lo, full_ln);
    k_select<<<24, 1024, 0, stream>>>(prior, selmask, lists, counts, qorder);
    k_high<<<3072, 64, 0, stream>>>(Qb, Kb, Vt, counts, lists, qorder, rowmax, prior,
                                    tc, Vh, full_lo, full_ln, mask, out);
}